// Round 1
// baseline (391.108 us; speedup 1.0000x reference)
//
#include <hip/hip_runtime.h>
#include <hip/hip_bf16.h>

// ---------------------------------------------------------------------------
// CausalSelfAttention: x[1,4096,1024] -> QKV -> 16-head causal attn -> out proj
// Round 0: correctness-first bf16 MFMA pipeline.
// ---------------------------------------------------------------------------

#define T_SEQ 4096
#define EMB   1024
#define NH    16
#define HD    64
#define N_QKV 3072

typedef __bf16 bf16x8 __attribute__((ext_vector_type(8)));
typedef __bf16 bf16x4 __attribute__((ext_vector_type(4)));
typedef float  f32x4  __attribute__((ext_vector_type(4)));

__device__ inline f32x4 mfma_16x16x32(bf16x8 a, bf16x8 b, f32x4 c) {
    return __builtin_amdgcn_mfma_f32_16x16x32_bf16(a, b, c, 0, 0, 0);
}

// ---------------------------------------------------------------------------
// fp32 -> bf16 elementwise (n divisible by 4)
// ---------------------------------------------------------------------------
__global__ __launch_bounds__(256) void f32_to_bf16_kernel(const float* __restrict__ in,
                                                          __bf16* __restrict__ out, int n) {
    int i = (blockIdx.x * 256 + threadIdx.x) * 4;
    if (i >= n) return;
    float4 v = *(const float4*)&in[i];
    bf16x4 o;
    o[0] = (__bf16)v.x; o[1] = (__bf16)v.y; o[2] = (__bf16)v.z; o[3] = (__bf16)v.w;
    *(bf16x4*)&out[i] = o;
}

// ---------------------------------------------------------------------------
// in [K][N] fp32 -> out [N][K] bf16 (32x32 tiles; K,N multiples of 32)
// ---------------------------------------------------------------------------
__global__ __launch_bounds__(256) void transpose_to_bf16_kernel(const float* __restrict__ in,
                                                                __bf16* __restrict__ out,
                                                                int K, int N) {
    __shared__ __bf16 tl[32][33];
    int k0 = blockIdx.x * 32, n0 = blockIdx.y * 32;
    int t = threadIdx.x;
    int r = t >> 3, c4 = (t & 7) * 4;
    float4 v = *(const float4*)&in[(size_t)(k0 + r) * N + n0 + c4];
    tl[r][c4 + 0] = (__bf16)v.x;
    tl[r][c4 + 1] = (__bf16)v.y;
    tl[r][c4 + 2] = (__bf16)v.z;
    tl[r][c4 + 3] = (__bf16)v.w;
    __syncthreads();
    bf16x4 o;
    o[0] = tl[c4 + 0][r];
    o[1] = tl[c4 + 1][r];
    o[2] = tl[c4 + 2][r];
    o[3] = tl[c4 + 3][r];
    *(bf16x4*)&out[(size_t)(n0 + r) * K + k0 + c4] = o;
}

// ---------------------------------------------------------------------------
// GEMM1: qkv = xb[4096][1024] @ wqkvT[3072][1024]^T + b_qkv
// Epilogue scatters to Q[h][t][d], K[h][t][d], VT[h][d][t] (bf16).
// 128x128 tile, 4 waves (2x2), BK=32.
// ---------------------------------------------------------------------------
__global__ __launch_bounds__(256) void gemm_qkv_kernel(const __bf16* __restrict__ A,
                                                       const __bf16* __restrict__ Bt,
                                                       const float* __restrict__ bias,
                                                       __bf16* __restrict__ Qo,
                                                       __bf16* __restrict__ Ko,
                                                       __bf16* __restrict__ VTo) {
    const int K = EMB;
    int m0 = blockIdx.y * 128, n0 = blockIdx.x * 128;
    int tid = threadIdx.x;
    int w = tid >> 6, l = tid & 63, lg = l >> 4, lr = l & 15;
    int wr = w >> 1, wc = w & 1;

    __shared__ __align__(16) __bf16 As[128][40];
    __shared__ __align__(16) __bf16 Bs[128][40];

    f32x4 acc[4][4];
#pragma unroll
    for (int mi = 0; mi < 4; ++mi)
#pragma unroll
        for (int ni = 0; ni < 4; ++ni) acc[mi][ni] = (f32x4){0.f, 0.f, 0.f, 0.f};

    for (int k0 = 0; k0 < K; k0 += 32) {
        __syncthreads();
#pragma unroll
        for (int i = 0; i < 2; ++i) {
            int flat = tid + 256 * i;
            int row = flat >> 2, ch = (flat & 3) * 8;
            *(bf16x8*)&As[row][ch] = *(const bf16x8*)&A[(size_t)(m0 + row) * K + k0 + ch];
            *(bf16x8*)&Bs[row][ch] = *(const bf16x8*)&Bt[(size_t)(n0 + row) * K + k0 + ch];
        }
        __syncthreads();
        bf16x8 af[4], bfr[4];
#pragma unroll
        for (int mi = 0; mi < 4; ++mi) af[mi] = *(const bf16x8*)&As[wr * 64 + mi * 16 + lr][lg * 8];
#pragma unroll
        for (int ni = 0; ni < 4; ++ni) bfr[ni] = *(const bf16x8*)&Bs[wc * 64 + ni * 16 + lr][lg * 8];
#pragma unroll
        for (int mi = 0; mi < 4; ++mi)
#pragma unroll
            for (int ni = 0; ni < 4; ++ni)
                acc[mi][ni] = mfma_16x16x32(af[mi], bfr[ni], acc[mi][ni]);
    }

    // epilogue: scatter to Q/K/VT
#pragma unroll
    for (int mi = 0; mi < 4; ++mi) {
#pragma unroll
        for (int ni = 0; ni < 4; ++ni) {
            int n = n0 + wc * 64 + ni * 16 + lr;
            float bv = bias[n];
            int mat = n >> 10, rem = n & 1023, h = rem >> 6, d = rem & 63;
#pragma unroll
            for (int r = 0; r < 4; ++r) {
                int m = m0 + wr * 64 + mi * 16 + lg * 4 + r;
                __bf16 cv = (__bf16)(acc[mi][ni][r] + bv);
                if (mat == 0) Qo[((size_t)h * T_SEQ + m) * HD + d];
                if (mat == 0) Qo[((size_t)h * T_SEQ + m) * HD + d] = cv;
                else if (mat == 1) Ko[((size_t)h * T_SEQ + m) * HD + d] = cv;
                else VTo[((size_t)h * HD + d) * T_SEQ + m] = cv;
            }
        }
    }
}

// ---------------------------------------------------------------------------
// Flash attention, causal. Block = (64 q-rows, 1 head), 4 waves x 16 rows.
// KV tiles of 64 staged in LDS; P via wave-private LDS round-trip.
// ---------------------------------------------------------------------------
__global__ __launch_bounds__(256) void attn_kernel(const __bf16* __restrict__ Qg,
                                                   const __bf16* __restrict__ Kg,
                                                   const __bf16* __restrict__ VTg,
                                                   __bf16* __restrict__ Og) {
    int h = blockIdx.y;
    int qb = blockIdx.x * 64;
    int tid = threadIdx.x;
    int w = tid >> 6, l = tid & 63, lg = l >> 4, lr = l & 15;

    __shared__ __align__(16) __bf16 Ks[64][72];  // [kv][d]
    __shared__ __align__(16) __bf16 Vs[64][72];  // [d][kv]
    __shared__ __align__(16) __bf16 Ps[4][16][64];

    const __bf16* Qh = Qg + (size_t)h * T_SEQ * HD;
    const __bf16* Kh = Kg + (size_t)h * T_SEQ * HD;
    const __bf16* Vh = VTg + (size_t)h * HD * T_SEQ;

    int qr0 = qb + 16 * w;

    bf16x8 qf[2];
    qf[0] = *(const bf16x8*)&Qh[(size_t)(qr0 + lr) * HD + lg * 8];
    qf[1] = *(const bf16x8*)&Qh[(size_t)(qr0 + lr) * HD + 32 + lg * 8];

    f32x4 oacc[4];
#pragma unroll
    for (int n = 0; n < 4; ++n) oacc[n] = (f32x4){0.f, 0.f, 0.f, 0.f};
    float mrow[4], lrow[4];
#pragma unroll
    for (int r = 0; r < 4; ++r) { mrow[r] = -1e30f; lrow[r] = 0.f; }

    const float scale = 0.125f;  // 1/sqrt(64)
    int ntiles = blockIdx.x + 1;

    for (int t = 0; t < ntiles; ++t) {
        int kv0 = t * 64;
        __syncthreads();
#pragma unroll
        for (int i = 0; i < 2; ++i) {
            int flat = tid + 256 * i;
            int row = flat >> 3, ch = (flat & 7) * 8;
            *(bf16x8*)&Ks[row][ch] = *(const bf16x8*)&Kh[(size_t)(kv0 + row) * HD + ch];
            *(bf16x8*)&Vs[row][ch] = *(const bf16x8*)&Vh[(size_t)row * T_SEQ + kv0 + ch];
        }
        __syncthreads();

        // S = Q @ K^T for 4 kv 16-col fragments
        f32x4 s[4];
#pragma unroll
        for (int b = 0; b < 4; ++b) {
            f32x4 a = (f32x4){0.f, 0.f, 0.f, 0.f};
#pragma unroll
            for (int kd = 0; kd < 2; ++kd) {
                bf16x8 kf = *(const bf16x8*)&Ks[b * 16 + lr][kd * 32 + lg * 8];
                a = mfma_16x16x32(qf[kd], kf, a);
            }
            s[b] = a;
        }

        // online softmax (per reg r, row q = qr0 + lg*4 + r)
#pragma unroll
        for (int r = 0; r < 4; ++r) {
            int q = qr0 + lg * 4 + r;
            float mx = -1e30f;
#pragma unroll
            for (int b = 0; b < 4; ++b) {
                int kv = kv0 + b * 16 + lr;
                float sv = s[b][r] * scale;
                sv = (kv <= q) ? sv : -1e30f;
                s[b][r] = sv;
                mx = fmaxf(mx, sv);
            }
#pragma unroll
            for (int d = 1; d < 16; d <<= 1) mx = fmaxf(mx, __shfl_xor(mx, d, 64));
            float mnew = fmaxf(mrow[r], mx);
            float alpha = __expf(mrow[r] - mnew);
            mrow[r] = mnew;
            lrow[r] *= alpha;
#pragma unroll
            for (int n = 0; n < 4; ++n) oacc[n][r] *= alpha;
            float ps = 0.f;
#pragma unroll
            for (int b = 0; b < 4; ++b) {
                float p = __expf(s[b][r] - mnew);
                s[b][r] = p;
                ps += p;
            }
#pragma unroll
            for (int d = 1; d < 16; d <<= 1) ps += __shfl_xor(ps, d, 64);
            lrow[r] += ps;
        }

        // P -> wave-private LDS (C-layout -> A-layout)
#pragma unroll
        for (int b = 0; b < 4; ++b)
#pragma unroll
            for (int r = 0; r < 4; ++r)
                Ps[w][lg * 4 + r][b * 16 + lr] = (__bf16)s[b][r];

        // O += P @ V  (V from transposed Vs[d][kv])
#pragma unroll
        for (int kd = 0; kd < 2; ++kd) {
            bf16x8 pa = *(const bf16x8*)&Ps[w][lr][kd * 32 + lg * 8];
#pragma unroll
            for (int n = 0; n < 4; ++n) {
                bf16x8 vb = *(const bf16x8*)&Vs[n * 16 + lr][kd * 32 + lg * 8];
                oacc[n] = mfma_16x16x32(pa, vb, oacc[n]);
            }
        }
    }

    // normalize + store to [t][e] bf16
#pragma unroll
    for (int r = 0; r < 4; ++r) {
        float inv = 1.0f / lrow[r];
        int q = qr0 + lg * 4 + r;
#pragma unroll
        for (int n = 0; n < 4; ++n) {
            int d = n * 16 + lr;
            Og[(size_t)q * EMB + h * HD + d] = (__bf16)(oacc[n][r] * inv);
        }
    }
}

// ---------------------------------------------------------------------------
// GEMM2: out = AO[4096][1024] @ woutT[1024][1024]^T + b_out  (fp32 out)
// ---------------------------------------------------------------------------
__global__ __launch_bounds__(256) void gemm_out_kernel(const __bf16* __restrict__ A,
                                                       const __bf16* __restrict__ Bt,
                                                       const float* __restrict__ bias,
                                                       float* __restrict__ out) {
    const int K = EMB;
    int m0 = blockIdx.y * 128, n0 = blockIdx.x * 128;
    int tid = threadIdx.x;
    int w = tid >> 6, l = tid & 63, lg = l >> 4, lr = l & 15;
    int wr = w >> 1, wc = w & 1;

    __shared__ __align__(16) __bf16 As[128][40];
    __shared__ __align__(16) __bf16 Bs[128][40];

    f32x4 acc[4][4];
#pragma unroll
    for (int mi = 0; mi < 4; ++mi)
#pragma unroll
        for (int ni = 0; ni < 4; ++ni) acc[mi][ni] = (f32x4){0.f, 0.f, 0.f, 0.f};

    for (int k0 = 0; k0 < K; k0 += 32) {
        __syncthreads();
#pragma unroll
        for (int i = 0; i < 2; ++i) {
            int flat = tid + 256 * i;
            int row = flat >> 2, ch = (flat & 3) * 8;
            *(bf16x8*)&As[row][ch] = *(const bf16x8*)&A[(size_t)(m0 + row) * K + k0 + ch];
            *(bf16x8*)&Bs[row][ch] = *(const bf16x8*)&Bt[(size_t)(n0 + row) * K + k0 + ch];
        }
        __syncthreads();
        bf16x8 af[4], bfr[4];
#pragma unroll
        for (int mi = 0; mi < 4; ++mi) af[mi] = *(const bf16x8*)&As[wr * 64 + mi * 16 + lr][lg * 8];
#pragma unroll
        for (int ni = 0; ni < 4; ++ni) bfr[ni] = *(const bf16x8*)&Bs[wc * 64 + ni * 16 + lr][lg * 8];
#pragma unroll
        for (int mi = 0; mi < 4; ++mi)
#pragma unroll
            for (int ni = 0; ni < 4; ++ni)
                acc[mi][ni] = mfma_16x16x32(af[mi], bfr[ni], acc[mi][ni]);
    }

#pragma unroll
    for (int mi = 0; mi < 4; ++mi) {
#pragma unroll
        for (int ni = 0; ni < 4; ++ni) {
            int n = n0 + wc * 64 + ni * 16 + lr;
            float bv = bias[n];
#pragma unroll
            for (int r = 0; r < 4; ++r) {
                int m = m0 + wr * 64 + mi * 16 + lg * 4 + r;
                out[(size_t)m * EMB + n] = acc[mi][ni][r] + bv;
            }
        }
    }
}

// ---------------------------------------------------------------------------
extern "C" void kernel_launch(void* const* d_in, const int* in_sizes, int n_in,
                              void* d_out, int out_size, void* d_ws, size_t ws_size,
                              hipStream_t stream) {
    const float* x      = (const float*)d_in[0];
    const float* w_qkv  = (const float*)d_in[1];
    const float* b_qkv  = (const float*)d_in[2];
    const float* w_out  = (const float*)d_in[3];
    const float* b_out  = (const float*)d_in[4];
    float* out = (float*)d_out;

    char* ws = (char*)d_ws;
    // layout (MiB): [0:8) xb / AO (aliased), [8:14) wqkvT, [14:16) woutT,
    //               [16:24) Q, [24:32) K, [32:40) VT   -> 40 MiB total
    __bf16* xb    = (__bf16*)(ws);
    __bf16* AO    = (__bf16*)(ws);                         // reuse after GEMM1 consumed xb
    __bf16* wqkvT = (__bf16*)(ws + ((size_t)8 << 20));
    __bf16* woutT = (__bf16*)(ws + ((size_t)14 << 20));
    __bf16* Qh    = (__bf16*)(ws + ((size_t)16 << 20));
    __bf16* Kh    = (__bf16*)(ws + ((size_t)24 << 20));
    __bf16* VTh   = (__bf16*)(ws + ((size_t)32 << 20));

    f32_to_bf16_kernel<<<dim3(T_SEQ * EMB / (256 * 4)), 256, 0, stream>>>(x, xb, T_SEQ * EMB);
    transpose_to_bf16_kernel<<<dim3(EMB / 32, N_QKV / 32), 256, 0, stream>>>(w_qkv, wqkvT, EMB, N_QKV);
    transpose_to_bf16_kernel<<<dim3(EMB / 32, EMB / 32), 256, 0, stream>>>(w_out, woutT, EMB, EMB);

    gemm_qkv_kernel<<<dim3(N_QKV / 128, T_SEQ / 128), 256, 0, stream>>>(xb, wqkvT, b_qkv, Qh, Kh, VTh);

    attn_kernel<<<dim3(T_SEQ / 64, NH), 256, 0, stream>>>(Qh, Kh, VTh, AO);

    gemm_out_kernel<<<dim3(EMB / 128, T_SEQ / 128), 256, 0, stream>>>(AO, woutT, b_out, out);
}

// Round 2
// 302.098 us; speedup vs baseline: 1.2946x; 1.2946x over previous
//
#include <hip/hip_runtime.h>
#include <hip/hip_bf16.h>

// ---------------------------------------------------------------------------
// CausalSelfAttention: x[1,4096,1024] -> QKV -> 16-head causal attn -> out proj
// Round 1: swapped-QK lane-local softmax + XOR-swizzled LDS + global_load_lds.
// ---------------------------------------------------------------------------

#define T_SEQ 4096
#define EMB   1024
#define NH    16
#define HD    64
#define N_QKV 3072

typedef __bf16 bf16x8 __attribute__((ext_vector_type(8)));
typedef __bf16 bf16x4 __attribute__((ext_vector_type(4)));
typedef float  f32x4  __attribute__((ext_vector_type(4)));

__device__ inline f32x4 mfma16(bf16x8 a, bf16x8 b, f32x4 c) {
    return __builtin_amdgcn_mfma_f32_16x16x32_bf16(a, b, c, 0, 0, 0);
}

// async global->LDS, 16B per lane. LDS dest must be wave-uniform base + lane*16.
__device__ inline void async_copy16(const void* g, void* l) {
    __builtin_amdgcn_global_load_lds(
        (const __attribute__((address_space(1))) unsigned int*)g,
        (__attribute__((address_space(3))) unsigned int*)l, 16, 0, 0);
}

// swizzled LDS read: 64-col bf16 rows (128B), byte ^= (row&7)<<4
__device__ inline bf16x8 lds_read8(const __bf16* base, int row, int colByte) {
    return *(const bf16x8*)((const char*)base + row * 128 +
                            (colByte ^ ((row & 7) << 4)));
}

// ---------------------------------------------------------------------------
// fp32 -> bf16 elementwise
// ---------------------------------------------------------------------------
__global__ __launch_bounds__(256) void f32_to_bf16_kernel(const float* __restrict__ in,
                                                          __bf16* __restrict__ out, int n) {
    int i = (blockIdx.x * 256 + threadIdx.x) * 4;
    if (i >= n) return;
    float4 v = *(const float4*)&in[i];
    bf16x4 o;
    o[0] = (__bf16)v.x; o[1] = (__bf16)v.y; o[2] = (__bf16)v.z; o[3] = (__bf16)v.w;
    *(bf16x4*)&out[i] = o;
}

// ---------------------------------------------------------------------------
// in [K][N] fp32 -> out [N][K] bf16
// ---------------------------------------------------------------------------
__global__ __launch_bounds__(256) void transpose_to_bf16_kernel(const float* __restrict__ in,
                                                                __bf16* __restrict__ out,
                                                                int K, int N) {
    __shared__ __bf16 tl[32][33];
    int k0 = blockIdx.x * 32, n0 = blockIdx.y * 32;
    int t = threadIdx.x;
    int r = t >> 3, c4 = (t & 7) * 4;
    float4 v = *(const float4*)&in[(size_t)(k0 + r) * N + n0 + c4];
    tl[r][c4 + 0] = (__bf16)v.x;
    tl[r][c4 + 1] = (__bf16)v.y;
    tl[r][c4 + 2] = (__bf16)v.z;
    tl[r][c4 + 3] = (__bf16)v.w;
    __syncthreads();
    bf16x4 o;
    o[0] = tl[c4 + 0][r];
    o[1] = tl[c4 + 1][r];
    o[2] = tl[c4 + 2][r];
    o[3] = tl[c4 + 3][r];
    *(bf16x4*)&out[(size_t)(n0 + r) * K + k0 + c4] = o;
}

// ---------------------------------------------------------------------------
// GEMM1: qkv = xb[4096][1024] @ wqkvT[3072][1024]^T + b_qkv  (m97 structure)
// K is pre-scaled by 1/8 (exact in bf16) so attention needs no scale.
// ---------------------------------------------------------------------------
__global__ __launch_bounds__(256) void gemm_qkv_kernel(const __bf16* __restrict__ A,
                                                       const __bf16* __restrict__ Bt,
                                                       const float* __restrict__ bias,
                                                       __bf16* __restrict__ Qo,
                                                       __bf16* __restrict__ Ko,
                                                       __bf16* __restrict__ VTo) {
    const int K = EMB;
    int m0 = blockIdx.y * 128, n0 = blockIdx.x * 128;
    int tid = threadIdx.x;
    int w = tid >> 6, l = tid & 63, lg = l >> 4, lr = l & 15;
    int wr = w >> 1, wc = w & 1;

    __shared__ __align__(16) __bf16 As[128 * 32];
    __shared__ __align__(16) __bf16 Bs[128 * 32];

    f32x4 acc[4][4];
#pragma unroll
    for (int mi = 0; mi < 4; ++mi)
#pragma unroll
        for (int ni = 0; ni < 4; ++ni) acc[mi][ni] = (f32x4){0.f, 0.f, 0.f, 0.f};

    for (int k0 = 0; k0 < K; k0 += 32) {
        __syncthreads();
#pragma unroll
        for (int i = 0; i < 2; ++i) {
            int flat = tid + 256 * i;
            int row = flat >> 2, c = flat & 3;
            async_copy16(&A[(size_t)(m0 + row) * K + k0 + c * 8], As + flat * 8);
            async_copy16(&Bt[(size_t)(n0 + row) * K + k0 + c * 8], Bs + flat * 8);
        }
        __syncthreads();
        bf16x8 af[4], bfr[4];
#pragma unroll
        for (int mi = 0; mi < 4; ++mi) af[mi] = *(const bf16x8*)(As + (wr * 64 + mi * 16 + lr) * 32 + lg * 8);
#pragma unroll
        for (int ni = 0; ni < 4; ++ni) bfr[ni] = *(const bf16x8*)(Bs + (wc * 64 + ni * 16 + lr) * 32 + lg * 8);
#pragma unroll
        for (int mi = 0; mi < 4; ++mi)
#pragma unroll
            for (int ni = 0; ni < 4; ++ni)
                acc[mi][ni] = mfma16(af[mi], bfr[ni], acc[mi][ni]);
    }

#pragma unroll
    for (int mi = 0; mi < 4; ++mi) {
#pragma unroll
        for (int ni = 0; ni < 4; ++ni) {
            int n = n0 + wc * 64 + ni * 16 + lr;
            float bv = bias[n];
            int mat = n >> 10, rem = n & 1023, hh = rem >> 6, d = rem & 63;
#pragma unroll
            for (int r = 0; r < 4; ++r) {
                int mr = m0 + wr * 64 + mi * 16 + lg * 4 + r;
                float v = acc[mi][ni][r] + bv;
                if (mat == 0)      Qo[((size_t)hh * T_SEQ + mr) * HD + d] = (__bf16)v;
                else if (mat == 1) Ko[((size_t)hh * T_SEQ + mr) * HD + d] = (__bf16)(v * 0.125f);
                else               VTo[((size_t)hh * HD + d) * T_SEQ + mr] = (__bf16)v;
            }
        }
    }
}

// ---------------------------------------------------------------------------
// Flash attention, causal. Block = (128 q-rows, 1 head), 4 waves x 32 rows
// (2 frags of 16). Swapped QK^T (S^T = mfma(K,Q)) -> softmax reduce over lg
// groups only (2 shfls). K/V/P LDS XOR-swizzled; K/V staged via
// global_load_lds with pre-swizzled global source.
// ---------------------------------------------------------------------------
__global__ __launch_bounds__(256) void attn_kernel(const __bf16* __restrict__ Qg,
                                                   const __bf16* __restrict__ Kg,
                                                   const __bf16* __restrict__ VTg,
                                                   __bf16* __restrict__ Og) {
    __shared__ __align__(16) __bf16 Ks[64 * 64];
    __shared__ __align__(16) __bf16 Vs[64 * 64];
    __shared__ __align__(16) __bf16 Ps[4][32 * 64];

    const int h = blockIdx.y;
    const int bx = (int)gridDim.x - 1 - (int)blockIdx.x;  // heavy blocks first
    const int qb = bx * 128;
    const int tid = threadIdx.x;
    const int w = tid >> 6, l = tid & 63, lg = l >> 4, lr = l & 15;
    const int qr0 = qb + 32 * w;

    const __bf16* Qh = Qg + (size_t)h * T_SEQ * HD;
    const __bf16* Kh = Kg + (size_t)h * T_SEQ * HD;
    const __bf16* Vh = VTg + (size_t)h * HD * T_SEQ;
    __bf16* PsW = &Ps[w][0];

    // Q fragments: Q[qr0+16f+lr][kd*32 + lg*8 ..]
    bf16x8 qf[2][2];
#pragma unroll
    for (int f = 0; f < 2; ++f)
#pragma unroll
        for (int kd = 0; kd < 2; ++kd)
            qf[f][kd] = *(const bf16x8*)&Qh[(size_t)(qr0 + 16 * f + lr) * HD + kd * 32 + lg * 8];

    f32x4 oacc[2][4];
#pragma unroll
    for (int f = 0; f < 2; ++f)
#pragma unroll
        for (int n = 0; n < 4; ++n) oacc[f][n] = (f32x4){0.f, 0.f, 0.f, 0.f};
    float m[2] = {-1e30f, -1e30f}, lsum[2] = {0.f, 0.f};

    const int ntiles = 2 * bx + 2;
    for (int t = 0; t < ntiles; ++t) {
        const int kv0 = t * 64;
        __syncthreads();
        // stage K,V with pre-swizzled source -> linear LDS dest (swizzled storage)
#pragma unroll
        for (int i = 0; i < 2; ++i) {
            int flat = tid + 256 * i;
            int row = flat >> 3, slot = flat & 7;
            int srcB = (slot * 16) ^ ((row & 7) << 4);
            async_copy16(Kh + (size_t)(kv0 + row) * HD + (srcB >> 1), Ks + flat * 8);
            async_copy16(Vh + (size_t)row * T_SEQ + kv0 + (srcB >> 1), Vs + flat * 8);
        }
        __syncthreads();

        const bool act0 = kv0 <= qr0 + 15;
        const bool act1 = kv0 <= qr0 + 31;
        if (!act1) continue;  // this wave done computing; keeps staging+barriers

        // K fragments (A-operand), reused across both q-frags
        bf16x8 kf[4][2];
#pragma unroll
        for (int blk = 0; blk < 4; ++blk)
#pragma unroll
            for (int kd = 0; kd < 2; ++kd)
                kf[blk][kd] = lds_read8(Ks, blk * 16 + lr, kd * 64 + lg * 16);

#pragma unroll
        for (int f = 0; f < 2; ++f) {
            if (f == 0 && !act0) continue;
            const int qfb = qr0 + 16 * f;
            // S^T[kv][q]: lane col = q = lr; row = kv = 16*blk + 4*lg + r
            f32x4 s[4];
#pragma unroll
            for (int blk = 0; blk < 4; ++blk) {
                f32x4 a = (f32x4){0.f, 0.f, 0.f, 0.f};
                a = mfma16(kf[blk][0], qf[f][0], a);
                a = mfma16(kf[blk][1], qf[f][1], a);
                s[blk] = a;
            }
            float mx = -1e30f;
            if (kv0 + 63 > qfb) {  // diagonal frag: apply causal mask
#pragma unroll
                for (int blk = 0; blk < 4; ++blk)
#pragma unroll
                    for (int r = 0; r < 4; ++r) {
                        int kv = kv0 + 16 * blk + 4 * lg + r;
                        float sv = (kv <= qfb + lr) ? s[blk][r] : -1e30f;
                        s[blk][r] = sv;
                        mx = fmaxf(mx, sv);
                    }
            } else {
#pragma unroll
                for (int blk = 0; blk < 4; ++blk)
#pragma unroll
                    for (int r = 0; r < 4; ++r) mx = fmaxf(mx, s[blk][r]);
            }
            mx = fmaxf(mx, __shfl_xor(mx, 16, 64));
            mx = fmaxf(mx, __shfl_xor(mx, 32, 64));
            float mnew = fmaxf(m[f], mx);
            float alpha = __expf(m[f] - mnew);
            m[f] = mnew;

            float ps = 0.f;
            const int prow = 16 * f + lr;
            char* pw = (char*)PsW + prow * 128;
            const int swz = (prow & 7) << 4;
#pragma unroll
            for (int blk = 0; blk < 4; ++blk) {
                bf16x4 pk;
#pragma unroll
                for (int r = 0; r < 4; ++r) {
                    float p = __expf(s[blk][r] - mnew);
                    ps += p;
                    pk[r] = (__bf16)p;
                }
                *(bf16x4*)(pw + ((32 * blk + 8 * lg) ^ swz)) = pk;
            }
            ps += __shfl_xor(ps, 16, 64);
            ps += __shfl_xor(ps, 32, 64);
            lsum[f] = lsum[f] * alpha + ps;

            // rescale O: O rows are q = 4*lg + r; alpha lives at lane lr == row
            float ar[4];
#pragma unroll
            for (int r = 0; r < 4; ++r) ar[r] = __shfl(alpha, 4 * lg + r, 64);
#pragma unroll
            for (int n = 0; n < 4; ++n)
#pragma unroll
                for (int r = 0; r < 4; ++r) oacc[f][n][r] *= ar[r];
        }

        // PV: O[q][d] += P[q][kv] * V[kv][d];  A = P (rows q), B = V^T (rows d)
#pragma unroll
        for (int kc = 0; kc < 2; ++kc) {
            bf16x8 pa1 = lds_read8(PsW, 16 + lr, kc * 64 + lg * 16);
            bf16x8 pa0 = pa1;
            if (act0) pa0 = lds_read8(PsW, lr, kc * 64 + lg * 16);
#pragma unroll
            for (int n = 0; n < 4; ++n) {
                bf16x8 vb = lds_read8(Vs, 16 * n + lr, kc * 64 + lg * 16);
                oacc[1][n] = mfma16(pa1, vb, oacc[1][n]);
                if (act0) oacc[0][n] = mfma16(pa0, vb, oacc[0][n]);
            }
        }
    }

    // normalize + store
#pragma unroll
    for (int f = 0; f < 2; ++f) {
        float linv = 1.0f / lsum[f];
        float lrv[4];
#pragma unroll
        for (int r = 0; r < 4; ++r) lrv[r] = __shfl(linv, 4 * lg + r, 64);
#pragma unroll
        for (int n = 0; n < 4; ++n)
#pragma unroll
            for (int r = 0; r < 4; ++r) {
                int q = qr0 + 16 * f + 4 * lg + r;
                Og[(size_t)q * EMB + h * HD + 16 * n + lr] = (__bf16)(oacc[f][n][r] * lrv[r]);
            }
    }
}

// ---------------------------------------------------------------------------
// GEMM2: out = AO[4096][1024] @ woutT[1024][1024]^T + b_out  (fp32 out)
// ---------------------------------------------------------------------------
__global__ __launch_bounds__(256) void gemm_out_kernel(const __bf16* __restrict__ A,
                                                       const __bf16* __restrict__ Bt,
                                                       const float* __restrict__ bias,
                                                       float* __restrict__ out) {
    const int K = EMB;
    int m0 = blockIdx.y * 128, n0 = blockIdx.x * 128;
    int tid = threadIdx.x;
    int w = tid >> 6, l = tid & 63, lg = l >> 4, lr = l & 15;
    int wr = w >> 1, wc = w & 1;

    __shared__ __align__(16) __bf16 As[128 * 32];
    __shared__ __align__(16) __bf16 Bs[128 * 32];

    f32x4 acc[4][4];
#pragma unroll
    for (int mi = 0; mi < 4; ++mi)
#pragma unroll
        for (int ni = 0; ni < 4; ++ni) acc[mi][ni] = (f32x4){0.f, 0.f, 0.f, 0.f};

    for (int k0 = 0; k0 < K; k0 += 32) {
        __syncthreads();
#pragma unroll
        for (int i = 0; i < 2; ++i) {
            int flat = tid + 256 * i;
            int row = flat >> 2, c = flat & 3;
            async_copy16(&A[(size_t)(m0 + row) * K + k0 + c * 8], As + flat * 8);
            async_copy16(&Bt[(size_t)(n0 + row) * K + k0 + c * 8], Bs + flat * 8);
        }
        __syncthreads();
        bf16x8 af[4], bfr[4];
#pragma unroll
        for (int mi = 0; mi < 4; ++mi) af[mi] = *(const bf16x8*)(As + (wr * 64 + mi * 16 + lr) * 32 + lg * 8);
#pragma unroll
        for (int ni = 0; ni < 4; ++ni) bfr[ni] = *(const bf16x8*)(Bs + (wc * 64 + ni * 16 + lr) * 32 + lg * 8);
#pragma unroll
        for (int mi = 0; mi < 4; ++mi)
#pragma unroll
            for (int ni = 0; ni < 4; ++ni)
                acc[mi][ni] = mfma16(af[mi], bfr[ni], acc[mi][ni]);
    }

#pragma unroll
    for (int mi = 0; mi < 4; ++mi) {
#pragma unroll
        for (int ni = 0; ni < 4; ++ni) {
            int n = n0 + wc * 64 + ni * 16 + lr;
            float bv = bias[n];
#pragma unroll
            for (int r = 0; r < 4; ++r) {
                int mr = m0 + wr * 64 + mi * 16 + lg * 4 + r;
                out[(size_t)mr * EMB + n] = acc[mi][ni][r] + bv;
            }
        }
    }
}

// ---------------------------------------------------------------------------
extern "C" void kernel_launch(void* const* d_in, const int* in_sizes, int n_in,
                              void* d_out, int out_size, void* d_ws, size_t ws_size,
                              hipStream_t stream) {
    const float* x      = (const float*)d_in[0];
    const float* w_qkv  = (const float*)d_in[1];
    const float* b_qkv  = (const float*)d_in[2];
    const float* w_out  = (const float*)d_in[3];
    const float* b_out  = (const float*)d_in[4];
    float* out = (float*)d_out;

    char* ws = (char*)d_ws;
    __bf16* xb    = (__bf16*)(ws);
    __bf16* AO    = (__bf16*)(ws);  // reuse after GEMM1 consumed xb
    __bf16* wqkvT = (__bf16*)(ws + ((size_t)8 << 20));
    __bf16* woutT = (__bf16*)(ws + ((size_t)14 << 20));
    __bf16* Qh    = (__bf16*)(ws + ((size_t)16 << 20));
    __bf16* Kh    = (__bf16*)(ws + ((size_t)24 << 20));
    __bf16* VTh   = (__bf16*)(ws + ((size_t)32 << 20));

    f32_to_bf16_kernel<<<dim3(T_SEQ * EMB / (256 * 4)), 256, 0, stream>>>(x, xb, T_SEQ * EMB);
    transpose_to_bf16_kernel<<<dim3(EMB / 32, N_QKV / 32), 256, 0, stream>>>(w_qkv, wqkvT, EMB, N_QKV);
    transpose_to_bf16_kernel<<<dim3(EMB / 32, EMB / 32), 256, 0, stream>>>(w_out, woutT, EMB, EMB);

    gemm_qkv_kernel<<<dim3(N_QKV / 128, T_SEQ / 128), 256, 0, stream>>>(xb, wqkvT, b_qkv, Qh, Kh, VTh);

    attn_kernel<<<dim3(T_SEQ / 128, NH), 256, 0, stream>>>(Qh, Kh, VTh, AO);

    gemm_out_kernel<<<dim3(EMB / 128, T_SEQ / 128), 256, 0, stream>>>(AO, woutT, b_out, out);
}

// Round 3
// 246.537 us; speedup vs baseline: 1.5864x; 1.2254x over previous
//
#include <hip/hip_runtime.h>
#include <hip/hip_bf16.h>

// ---------------------------------------------------------------------------
// CausalSelfAttention: x[1,4096,1024] -> QKV -> 16-head causal attn -> out proj
// Round 2: 8-wave dbuf attn (1 barrier/tile), log2 softmax + defer-max,
//          coalesced V + separate transpose, setprio, XCD head grouping.
// ---------------------------------------------------------------------------

#define T_SEQ 4096
#define EMB   1024
#define NH    16
#define HD    64
#define N_QKV 3072

typedef __bf16 bf16x8 __attribute__((ext_vector_type(8)));
typedef __bf16 bf16x4 __attribute__((ext_vector_type(4)));
typedef float  f32x4  __attribute__((ext_vector_type(4)));

__device__ inline f32x4 mfma16(bf16x8 a, bf16x8 b, f32x4 c) {
    return __builtin_amdgcn_mfma_f32_16x16x32_bf16(a, b, c, 0, 0, 0);
}

__device__ inline void async_copy16(const void* g, void* l) {
    __builtin_amdgcn_global_load_lds(
        (const __attribute__((address_space(1))) unsigned int*)g,
        (__attribute__((address_space(3))) unsigned int*)l, 16, 0, 0);
}

// swizzled LDS read: 64-col bf16 rows (128B), byte ^= (row&7)<<4
__device__ inline bf16x8 lds_read8(const __bf16* base, int row, int colByte) {
    return *(const bf16x8*)((const char*)base + row * 128 +
                            (colByte ^ ((row & 7) << 4)));
}

// ---------------------------------------------------------------------------
__global__ __launch_bounds__(256) void f32_to_bf16_kernel(const float* __restrict__ in,
                                                          __bf16* __restrict__ out, int n) {
    int i = (blockIdx.x * 256 + threadIdx.x) * 4;
    if (i >= n) return;
    float4 v = *(const float4*)&in[i];
    bf16x4 o;
    o[0] = (__bf16)v.x; o[1] = (__bf16)v.y; o[2] = (__bf16)v.z; o[3] = (__bf16)v.w;
    *(bf16x4*)&out[i] = o;
}

// ---------------------------------------------------------------------------
__global__ __launch_bounds__(256) void transpose_to_bf16_kernel(const float* __restrict__ in,
                                                                __bf16* __restrict__ out,
                                                                int K, int N) {
    __shared__ __bf16 tl[32][33];
    int k0 = blockIdx.x * 32, n0 = blockIdx.y * 32;
    int t = threadIdx.x;
    int r = t >> 3, c4 = (t & 7) * 4;
    float4 v = *(const float4*)&in[(size_t)(k0 + r) * N + n0 + c4];
    tl[r][c4 + 0] = (__bf16)v.x;
    tl[r][c4 + 1] = (__bf16)v.y;
    tl[r][c4 + 2] = (__bf16)v.z;
    tl[r][c4 + 3] = (__bf16)v.w;
    __syncthreads();
    bf16x4 o;
    o[0] = tl[c4 + 0][r];
    o[1] = tl[c4 + 1][r];
    o[2] = tl[c4 + 2][r];
    o[3] = tl[c4 + 3][r];
    *(bf16x4*)&out[(size_t)(n0 + r) * K + k0 + c4] = o;
}

// ---------------------------------------------------------------------------
// GEMM1: qkv = xb @ wqkvT^T + b_qkv. Q pre-scaled by 0.125*log2(e) (softmax
// runs in log2 domain). Q,K,V all written [h][t][d] coalesced.
// ---------------------------------------------------------------------------
__global__ __launch_bounds__(256) void gemm_qkv_kernel(const __bf16* __restrict__ A,
                                                       const __bf16* __restrict__ Bt,
                                                       const float* __restrict__ bias,
                                                       __bf16* __restrict__ Qo,
                                                       __bf16* __restrict__ Ko,
                                                       __bf16* __restrict__ Vo) {
    const int K = EMB;
    int m0 = blockIdx.y * 128, n0 = blockIdx.x * 128;
    int tid = threadIdx.x;
    int w = tid >> 6, l = tid & 63, lg = l >> 4, lr = l & 15;
    int wr = w >> 1, wc = w & 1;

    __shared__ __align__(16) __bf16 As[128 * 32];
    __shared__ __align__(16) __bf16 Bs[128 * 32];

    f32x4 acc[4][4];
#pragma unroll
    for (int mi = 0; mi < 4; ++mi)
#pragma unroll
        for (int ni = 0; ni < 4; ++ni) acc[mi][ni] = (f32x4){0.f, 0.f, 0.f, 0.f};

    for (int k0 = 0; k0 < K; k0 += 32) {
        __syncthreads();
#pragma unroll
        for (int i = 0; i < 2; ++i) {
            int flat = tid + 256 * i;
            int row = flat >> 2, c = flat & 3;
            async_copy16(&A[(size_t)(m0 + row) * K + k0 + c * 8], As + flat * 8);
            async_copy16(&Bt[(size_t)(n0 + row) * K + k0 + c * 8], Bs + flat * 8);
        }
        __syncthreads();
        bf16x8 af[4], bfr[4];
#pragma unroll
        for (int mi = 0; mi < 4; ++mi) af[mi] = *(const bf16x8*)(As + (wr * 64 + mi * 16 + lr) * 32 + lg * 8);
#pragma unroll
        for (int ni = 0; ni < 4; ++ni) bfr[ni] = *(const bf16x8*)(Bs + (wc * 64 + ni * 16 + lr) * 32 + lg * 8);
#pragma unroll
        for (int mi = 0; mi < 4; ++mi)
#pragma unroll
            for (int ni = 0; ni < 4; ++ni)
                acc[mi][ni] = mfma16(af[mi], bfr[ni], acc[mi][ni]);
    }

    const float QSC = 0.18033688011112042f;  // 0.125 * log2(e)
#pragma unroll
    for (int mi = 0; mi < 4; ++mi) {
#pragma unroll
        for (int ni = 0; ni < 4; ++ni) {
            int n = n0 + wc * 64 + ni * 16 + lr;
            float bv = bias[n];
            int mat = n >> 10, rem = n & 1023, hh = rem >> 6, d = rem & 63;
#pragma unroll
            for (int r = 0; r < 4; ++r) {
                int mr = m0 + wr * 64 + mi * 16 + lg * 4 + r;
                float v = acc[mi][ni][r] + bv;
                size_t idx = ((size_t)hh * T_SEQ + mr) * HD + d;
                if (mat == 0)      Qo[idx] = (__bf16)(v * QSC);
                else if (mat == 1) Ko[idx] = (__bf16)v;
                else               Vo[idx] = (__bf16)v;
            }
        }
    }
}

// ---------------------------------------------------------------------------
// V [h][t][d] -> VT [h][d][t]  (vectorized LDS transpose, 64x64 tiles)
// ---------------------------------------------------------------------------
__global__ __launch_bounds__(256) void vt_kernel(const __bf16* __restrict__ V,
                                                 __bf16* __restrict__ VT) {
    __shared__ __bf16 tl[64][72];
    int h = blockIdx.y, t0 = blockIdx.x * 64;
    int tid = threadIdx.x;
    const __bf16* Vh = V + (size_t)h * T_SEQ * HD;
#pragma unroll
    for (int i = 0; i < 2; ++i) {
        int flat = tid + 256 * i;
        int r = flat >> 3, sl = flat & 7;
        *(bf16x8*)&tl[r][sl * 8] = *(const bf16x8*)&Vh[(size_t)(t0 + r) * HD + sl * 8];
    }
    __syncthreads();
    __bf16* VTh = VT + (size_t)h * HD * T_SEQ;
#pragma unroll
    for (int i = 0; i < 2; ++i) {
        int flat = tid + 256 * i;
        int d = flat >> 3, sl = flat & 7;
        bf16x8 o;
#pragma unroll
        for (int j = 0; j < 8; ++j) o[j] = tl[sl * 8 + j][d];
        *(bf16x8*)&VTh[(size_t)d * T_SEQ + t0 + sl * 8] = o;
    }
}

// ---------------------------------------------------------------------------
// Flash attention, causal, log2 domain. 512 threads = 8 waves x 16 q-rows.
// Double-buffered K/V (global_load_lds, swizzled storage), ONE barrier/tile.
// Swapped QK^T -> lane-local softmax rows; defer-max rescale (THR=8 log2).
// ---------------------------------------------------------------------------
__global__ __launch_bounds__(512) void attn_kernel(const __bf16* __restrict__ Qg,
                                                   const __bf16* __restrict__ Kg,
                                                   const __bf16* __restrict__ VTg,
                                                   __bf16* __restrict__ Og) {
    __shared__ __align__(16) __bf16 Ks[2][64 * 64];
    __shared__ __align__(16) __bf16 Vs[2][64 * 64];
    __shared__ __align__(16) __bf16 Ps[8][16 * 64];

    const int bid = blockIdx.x;
    const int xcd = bid & 7, li = bid >> 3;
    const int h = xcd * 2 + (li & 1);      // 2 heads per XCD -> K/V L2-resident
    const int bx = 31 - (li >> 1);         // heavy blocks first
    const int qb = bx * 128;
    const int tid = threadIdx.x;
    const int w = tid >> 6, l = tid & 63, lg = l >> 4, lr = l & 15;
    const int qr0 = qb + 16 * w;

    const __bf16* Qh = Qg + (size_t)h * T_SEQ * HD;
    const __bf16* Kh = Kg + (size_t)h * T_SEQ * HD;
    const __bf16* Vh = VTg + (size_t)h * HD * T_SEQ;
    __bf16* PsW = &Ps[w][0];

    // staging geometry: 512 lanes x 16B = one 64x64 bf16 tile per instruction
    const int srow = tid >> 3, sslot = tid & 7;
    const int sB = (sslot * 16) ^ ((srow & 7) << 4);   // pre-swizzled source
    const size_t kOff = (size_t)srow * HD + (sB >> 1);
    const size_t vOff = (size_t)srow * T_SEQ + (sB >> 1);

    bf16x8 qf[2];
#pragma unroll
    for (int kd = 0; kd < 2; ++kd)
        qf[kd] = *(const bf16x8*)&Qh[(size_t)(qr0 + lr) * HD + kd * 32 + lg * 8];

    f32x4 oacc[4];
#pragma unroll
    for (int n = 0; n < 4; ++n) oacc[n] = (f32x4){0.f, 0.f, 0.f, 0.f};
    float m = -1e30f, lsum = 0.f;

    const int ntiles = 2 * bx + 2;

    // prologue: stage tile 0 -> buf 0
    async_copy16(Kh + kOff, &Ks[0][tid * 8]);
    async_copy16(Vh + vOff, &Vs[0][tid * 8]);
    __syncthreads();

    int cur = 0;
    for (int t = 0; t < ntiles; ++t) {
        const int kv0 = t * 64;
        if (t + 1 < ntiles) {  // issue next tile's loads; drained by loop-end barrier
            async_copy16(Kh + (size_t)(t + 1) * 64 * HD + kOff, &Ks[cur ^ 1][tid * 8]);
            async_copy16(Vh + (size_t)(t + 1) * 64 + vOff, &Vs[cur ^ 1][tid * 8]);
        }
        if (kv0 <= qr0 + 15) {
            const __bf16* Ksc = &Ks[cur][0];
            const __bf16* Vsc = &Vs[cur][0];

            bf16x8 kf[4][2];
#pragma unroll
            for (int blk = 0; blk < 4; ++blk)
#pragma unroll
                for (int kd = 0; kd < 2; ++kd)
                    kf[blk][kd] = lds_read8(Ksc, blk * 16 + lr, kd * 64 + lg * 16);

            __builtin_amdgcn_s_setprio(1);
            f32x4 s[4];
#pragma unroll
            for (int blk = 0; blk < 4; ++blk) {
                f32x4 a = (f32x4){0.f, 0.f, 0.f, 0.f};
                a = mfma16(kf[blk][0], qf[0], a);
                a = mfma16(kf[blk][1], qf[1], a);
                s[blk] = a;
            }
            __builtin_amdgcn_s_setprio(0);

            float mx = -1e30f;
            if (kv0 + 63 > qr0) {  // diagonal tile: causal mask
#pragma unroll
                for (int blk = 0; blk < 4; ++blk)
#pragma unroll
                    for (int r = 0; r < 4; ++r) {
                        int kv = kv0 + 16 * blk + 4 * lg + r;
                        float sv = (kv <= qr0 + lr) ? s[blk][r] : -1e30f;
                        s[blk][r] = sv;
                        mx = fmaxf(mx, sv);
                    }
            } else {
#pragma unroll
                for (int blk = 0; blk < 4; ++blk)
#pragma unroll
                    for (int r = 0; r < 4; ++r) mx = fmaxf(mx, s[blk][r]);
            }
            mx = fmaxf(mx, __shfl_xor(mx, 16, 64));
            mx = fmaxf(mx, __shfl_xor(mx, 32, 64));

            // defer-max: skip rescale unless max grew by >8 (log2 units)
            if (!__all(mx <= m + 8.f)) {
                float mnew = fmaxf(m, mx);
                float alpha = exp2f(m - mnew);
                m = mnew;
                lsum *= alpha;
                float ar[4];
#pragma unroll
                for (int r = 0; r < 4; ++r) ar[r] = __shfl(alpha, 4 * lg + r, 64);
#pragma unroll
                for (int n = 0; n < 4; ++n)
#pragma unroll
                    for (int r = 0; r < 4; ++r) oacc[n][r] *= ar[r];
            }

            float ps = 0.f;
            char* pw = (char*)PsW + lr * 128;
            const int swz = (lr & 7) << 4;
#pragma unroll
            for (int blk = 0; blk < 4; ++blk) {
                bf16x4 pk;
#pragma unroll
                for (int r = 0; r < 4; ++r) {
                    float p = exp2f(s[blk][r] - m);
                    ps += p;
                    pk[r] = (__bf16)p;
                }
                *(bf16x4*)(pw + ((32 * blk + 8 * lg) ^ swz)) = pk;
            }
            ps += __shfl_xor(ps, 16, 64);
            ps += __shfl_xor(ps, 32, 64);
            lsum += ps;

            __builtin_amdgcn_s_setprio(1);
#pragma unroll
            for (int kc = 0; kc < 2; ++kc) {
                bf16x8 pa = lds_read8(PsW, lr, kc * 64 + lg * 16);
#pragma unroll
                for (int n = 0; n < 4; ++n) {
                    bf16x8 vb = lds_read8(Vsc, 16 * n + lr, kc * 64 + lg * 16);
                    oacc[n] = mfma16(pa, vb, oacc[n]);
                }
            }
            __builtin_amdgcn_s_setprio(0);
        }
        __syncthreads();  // drains next-tile loads (vmcnt 0) + frees P/K/V bufs
        cur ^= 1;
    }

    float linv = 1.0f / lsum;
    float lrv[4];
#pragma unroll
    for (int r = 0; r < 4; ++r) lrv[r] = __shfl(linv, 4 * lg + r, 64);
#pragma unroll
    for (int n = 0; n < 4; ++n)
#pragma unroll
        for (int r = 0; r < 4; ++r) {
            int q = qr0 + 4 * lg + r;
            Og[(size_t)q * EMB + h * HD + 16 * n + lr] = (__bf16)(oacc[n][r] * lrv[r]);
        }
}

// ---------------------------------------------------------------------------
// GEMM2: out = AO @ woutT^T + b_out (fp32 out)
// ---------------------------------------------------------------------------
__global__ __launch_bounds__(256) void gemm_out_kernel(const __bf16* __restrict__ A,
                                                       const __bf16* __restrict__ Bt,
                                                       const float* __restrict__ bias,
                                                       float* __restrict__ out) {
    const int K = EMB;
    int m0 = blockIdx.y * 128, n0 = blockIdx.x * 128;
    int tid = threadIdx.x;
    int w = tid >> 6, l = tid & 63, lg = l >> 4, lr = l & 15;
    int wr = w >> 1, wc = w & 1;

    __shared__ __align__(16) __bf16 As[128 * 32];
    __shared__ __align__(16) __bf16 Bs[128 * 32];

    f32x4 acc[4][4];
#pragma unroll
    for (int mi = 0; mi < 4; ++mi)
#pragma unroll
        for (int ni = 0; ni < 4; ++ni) acc[mi][ni] = (f32x4){0.f, 0.f, 0.f, 0.f};

    for (int k0 = 0; k0 < K; k0 += 32) {
        __syncthreads();
#pragma unroll
        for (int i = 0; i < 2; ++i) {
            int flat = tid + 256 * i;
            int row = flat >> 2, c = flat & 3;
            async_copy16(&A[(size_t)(m0 + row) * K + k0 + c * 8], As + flat * 8);
            async_copy16(&Bt[(size_t)(n0 + row) * K + k0 + c * 8], Bs + flat * 8);
        }
        __syncthreads();
        bf16x8 af[4], bfr[4];
#pragma unroll
        for (int mi = 0; mi < 4; ++mi) af[mi] = *(const bf16x8*)(As + (wr * 64 + mi * 16 + lr) * 32 + lg * 8);
#pragma unroll
        for (int ni = 0; ni < 4; ++ni) bfr[ni] = *(const bf16x8*)(Bs + (wc * 64 + ni * 16 + lr) * 32 + lg * 8);
#pragma unroll
        for (int mi = 0; mi < 4; ++mi)
#pragma unroll
            for (int ni = 0; ni < 4; ++ni)
                acc[mi][ni] = mfma16(af[mi], bfr[ni], acc[mi][ni]);
    }

#pragma unroll
    for (int mi = 0; mi < 4; ++mi) {
#pragma unroll
        for (int ni = 0; ni < 4; ++ni) {
            int n = n0 + wc * 64 + ni * 16 + lr;
            float bv = bias[n];
#pragma unroll
            for (int r = 0; r < 4; ++r) {
                int mr = m0 + wr * 64 + mi * 16 + lg * 4 + r;
                out[(size_t)mr * EMB + n] = acc[mi][ni][r] + bv;
            }
        }
    }
}

// ---------------------------------------------------------------------------
extern "C" void kernel_launch(void* const* d_in, const int* in_sizes, int n_in,
                              void* d_out, int out_size, void* d_ws, size_t ws_size,
                              hipStream_t stream) {
    const float* x      = (const float*)d_in[0];
    const float* w_qkv  = (const float*)d_in[1];
    const float* b_qkv  = (const float*)d_in[2];
    const float* w_out  = (const float*)d_in[3];
    const float* b_out  = (const float*)d_in[4];
    float* out = (float*)d_out;

    char* ws = (char*)d_ws;
    __bf16* xb    = (__bf16*)(ws);                      // 8 MiB, reused as AO
    __bf16* AO    = (__bf16*)(ws);
    __bf16* wqkvT = (__bf16*)(ws + ((size_t)8 << 20));  // 6 MiB
    __bf16* woutT = (__bf16*)(ws + ((size_t)14 << 20)); // 2 MiB
    __bf16* Qh    = (__bf16*)(ws + ((size_t)16 << 20)); // 8 MiB
    __bf16* Kh    = (__bf16*)(ws + ((size_t)24 << 20)); // 8 MiB
    __bf16* Vh    = (__bf16*)(ws + ((size_t)32 << 20)); // 8 MiB
    __bf16* VTh   = (__bf16*)(ws + ((size_t)40 << 20)); // 8 MiB

    f32_to_bf16_kernel<<<dim3(T_SEQ * EMB / (256 * 4)), 256, 0, stream>>>(x, xb, T_SEQ * EMB);
    transpose_to_bf16_kernel<<<dim3(EMB / 32, N_QKV / 32), 256, 0, stream>>>(w_qkv, wqkvT, EMB, N_QKV);
    transpose_to_bf16_kernel<<<dim3(EMB / 32, EMB / 32), 256, 0, stream>>>(w_out, woutT, EMB, EMB);

    gemm_qkv_kernel<<<dim3(N_QKV / 128, T_SEQ / 128), 256, 0, stream>>>(xb, wqkvT, b_qkv, Qh, Kh, Vh);

    vt_kernel<<<dim3(T_SEQ / 64, NH), 256, 0, stream>>>(Vh, VTh);

    attn_kernel<<<dim3(512), 512, 0, stream>>>(Qh, Kh, VTh, AO);

    gemm_out_kernel<<<dim3(EMB / 128, T_SEQ / 128), 256, 0, stream>>>(AO, woutT, b_out, out);
}

// Round 4
// 231.861 us; speedup vs baseline: 1.6868x; 1.0633x over previous
//
#include <hip/hip_runtime.h>
#include <hip/hip_bf16.h>

// ---------------------------------------------------------------------------
// CausalSelfAttention: x[1,4096,1024] -> QKV -> 16-head causal attn -> out proj
// Round 3: balanced attn grid (QBLK=64, 4 blocks/CU, pair-sum-constant work
//          mapping), fused prep kernel. Attn math unchanged from round 2.
// ---------------------------------------------------------------------------

#define T_SEQ 4096
#define EMB   1024
#define NH    16
#define HD    64
#define N_QKV 3072

typedef __bf16 bf16x8 __attribute__((ext_vector_type(8)));
typedef __bf16 bf16x4 __attribute__((ext_vector_type(4)));
typedef float  f32x4  __attribute__((ext_vector_type(4)));

__device__ inline f32x4 mfma16(bf16x8 a, bf16x8 b, f32x4 c) {
    return __builtin_amdgcn_mfma_f32_16x16x32_bf16(a, b, c, 0, 0, 0);
}

__device__ inline void async_copy16(const void* g, void* l) {
    __builtin_amdgcn_global_load_lds(
        (const __attribute__((address_space(1))) unsigned int*)g,
        (__attribute__((address_space(3))) unsigned int*)l, 16, 0, 0);
}

// swizzled LDS read: 64-col bf16 rows (128B), byte ^= (row&7)<<4
__device__ inline bf16x8 lds_read8(const __bf16* base, int row, int colByte) {
    return *(const bf16x8*)((const char*)base + row * 128 +
                            (colByte ^ ((row & 7) << 4)));
}

// ---------------------------------------------------------------------------
// Fused prep: [0,4096) x->bf16 convert, [4096,7168) w_qkv transpose,
// [7168,8192) w_out transpose.
// ---------------------------------------------------------------------------
__global__ __launch_bounds__(256) void prep_kernel(const float* __restrict__ x,
                                                   const float* __restrict__ w_qkv,
                                                   const float* __restrict__ w_out,
                                                   __bf16* __restrict__ xb,
                                                   __bf16* __restrict__ wqkvT,
                                                   __bf16* __restrict__ woutT) {
    __shared__ __bf16 tl[32][33];
    int b = blockIdx.x;
    int t = threadIdx.x;
    if (b < 4096) {
        int i = (b * 256 + t) * 4;
        float4 v = *(const float4*)&x[i];
        bf16x4 o;
        o[0] = (__bf16)v.x; o[1] = (__bf16)v.y; o[2] = (__bf16)v.z; o[3] = (__bf16)v.w;
        *(bf16x4*)&xb[i] = o;
        return;
    }
    const float* in;
    __bf16* out;
    int N, bb;
    if (b < 7168) { bb = b - 4096; in = w_qkv; out = wqkvT; N = N_QKV; }
    else          { bb = b - 7168; in = w_out; out = woutT; N = EMB; }
    int k0 = (bb & 31) * 32, n0 = (bb >> 5) * 32;
    int r = t >> 3, c4 = (t & 7) * 4;
    float4 v = *(const float4*)&in[(size_t)(k0 + r) * N + n0 + c4];
    tl[r][c4 + 0] = (__bf16)v.x;
    tl[r][c4 + 1] = (__bf16)v.y;
    tl[r][c4 + 2] = (__bf16)v.z;
    tl[r][c4 + 3] = (__bf16)v.w;
    __syncthreads();
    bf16x4 o;
    o[0] = tl[c4 + 0][r];
    o[1] = tl[c4 + 1][r];
    o[2] = tl[c4 + 2][r];
    o[3] = tl[c4 + 3][r];
    *(bf16x4*)&out[(size_t)(n0 + r) * EMB + k0 + c4] = o;
}

// ---------------------------------------------------------------------------
// GEMM1: qkv = xb @ wqkvT^T + b_qkv. Q pre-scaled by 0.125*log2(e) (softmax
// runs in log2 domain). Q,K,V all written [h][t][d] coalesced.
// ---------------------------------------------------------------------------
__global__ __launch_bounds__(256) void gemm_qkv_kernel(const __bf16* __restrict__ A,
                                                       const __bf16* __restrict__ Bt,
                                                       const float* __restrict__ bias,
                                                       __bf16* __restrict__ Qo,
                                                       __bf16* __restrict__ Ko,
                                                       __bf16* __restrict__ Vo) {
    const int K = EMB;
    int m0 = blockIdx.y * 128, n0 = blockIdx.x * 128;
    int tid = threadIdx.x;
    int w = tid >> 6, l = tid & 63, lg = l >> 4, lr = l & 15;
    int wr = w >> 1, wc = w & 1;

    __shared__ __align__(16) __bf16 As[128 * 32];
    __shared__ __align__(16) __bf16 Bs[128 * 32];

    f32x4 acc[4][4];
#pragma unroll
    for (int mi = 0; mi < 4; ++mi)
#pragma unroll
        for (int ni = 0; ni < 4; ++ni) acc[mi][ni] = (f32x4){0.f, 0.f, 0.f, 0.f};

    for (int k0 = 0; k0 < K; k0 += 32) {
        __syncthreads();
#pragma unroll
        for (int i = 0; i < 2; ++i) {
            int flat = tid + 256 * i;
            int row = flat >> 2, c = flat & 3;
            async_copy16(&A[(size_t)(m0 + row) * K + k0 + c * 8], As + flat * 8);
            async_copy16(&Bt[(size_t)(n0 + row) * K + k0 + c * 8], Bs + flat * 8);
        }
        __syncthreads();
        bf16x8 af[4], bfr[4];
#pragma unroll
        for (int mi = 0; mi < 4; ++mi) af[mi] = *(const bf16x8*)(As + (wr * 64 + mi * 16 + lr) * 32 + lg * 8);
#pragma unroll
        for (int ni = 0; ni < 4; ++ni) bfr[ni] = *(const bf16x8*)(Bs + (wc * 64 + ni * 16 + lr) * 32 + lg * 8);
#pragma unroll
        for (int mi = 0; mi < 4; ++mi)
#pragma unroll
            for (int ni = 0; ni < 4; ++ni)
                acc[mi][ni] = mfma16(af[mi], bfr[ni], acc[mi][ni]);
    }

    const float QSC = 0.18033688011112042f;  // 0.125 * log2(e)
#pragma unroll
    for (int mi = 0; mi < 4; ++mi) {
#pragma unroll
        for (int ni = 0; ni < 4; ++ni) {
            int n = n0 + wc * 64 + ni * 16 + lr;
            float bv = bias[n];
            int mat = n >> 10, rem = n & 1023, hh = rem >> 6, d = rem & 63;
#pragma unroll
            for (int r = 0; r < 4; ++r) {
                int mr = m0 + wr * 64 + mi * 16 + lg * 4 + r;
                float v = acc[mi][ni][r] + bv;
                size_t idx = ((size_t)hh * T_SEQ + mr) * HD + d;
                if (mat == 0)      Qo[idx] = (__bf16)(v * QSC);
                else if (mat == 1) Ko[idx] = (__bf16)v;
                else               Vo[idx] = (__bf16)v;
            }
        }
    }
}

// ---------------------------------------------------------------------------
// V [h][t][d] -> VT [h][d][t]  (vectorized LDS transpose, 64x64 tiles)
// ---------------------------------------------------------------------------
__global__ __launch_bounds__(256) void vt_kernel(const __bf16* __restrict__ V,
                                                 __bf16* __restrict__ VT) {
    __shared__ __bf16 tl[64][72];
    int h = blockIdx.y, t0 = blockIdx.x * 64;
    int tid = threadIdx.x;
    const __bf16* Vh = V + (size_t)h * T_SEQ * HD;
#pragma unroll
    for (int i = 0; i < 2; ++i) {
        int flat = tid + 256 * i;
        int r = flat >> 3, sl = flat & 7;
        *(bf16x8*)&tl[r][sl * 8] = *(const bf16x8*)&Vh[(size_t)(t0 + r) * HD + sl * 8];
    }
    __syncthreads();
    __bf16* VTh = VT + (size_t)h * HD * T_SEQ;
#pragma unroll
    for (int i = 0; i < 2; ++i) {
        int flat = tid + 256 * i;
        int d = flat >> 3, sl = flat & 7;
        bf16x8 o;
#pragma unroll
        for (int j = 0; j < 8; ++j) o[j] = tl[sl * 8 + j][d];
        *(bf16x8*)&VTh[(size_t)d * T_SEQ + t0 + sl * 8] = o;
    }
}

// ---------------------------------------------------------------------------
// Flash attention, causal, log2 domain. 256 threads = 4 waves x 16 q-rows,
// QBLK=64. Balanced grid: 1024 blocks (4/CU), pair-sum-constant bx mapping,
// 2 heads per XCD. Double-buffered K/V via global_load_lds (swizzled),
// ONE barrier/tile; swapped QK^T lane-local softmax; defer-max.
// ---------------------------------------------------------------------------
__global__ __launch_bounds__(256) void attn_kernel(const __bf16* __restrict__ Qg,
                                                   const __bf16* __restrict__ Kg,
                                                   const __bf16* __restrict__ VTg,
                                                   __bf16* __restrict__ Og) {
    __shared__ __align__(16) __bf16 Ks[2][64 * 64];
    __shared__ __align__(16) __bf16 Vs[2][64 * 64];
    __shared__ __align__(16) __bf16 Ps[4][16 * 64];

    const int bid = blockIdx.x;
    const int xcd = bid & 7, li = bid >> 3;
    const int h = xcd * 2 + (li & 1);          // 2 heads per XCD
    const int j = li >> 1;                     // 0..63
    const int bx = (j < 32) ? (63 - j) : (j - 32);  // CU quad sums to 130 units
    const int qb = bx * 64;
    const int tid = threadIdx.x;
    const int w = tid >> 6, l = tid & 63, lg = l >> 4, lr = l & 15;
    const int qr0 = qb + 16 * w;

    const __bf16* Qh = Qg + (size_t)h * T_SEQ * HD;
    const __bf16* Kh = Kg + (size_t)h * T_SEQ * HD;
    const __bf16* Vh = VTg + (size_t)h * HD * T_SEQ;
    __bf16* PsW = &Ps[w][0];

    // staging: 256 lanes x 16B = 32 rows per issue; 2 issues per 64-row tile
    const int srow = tid >> 3, sslot = tid & 7;
    const int sB = (sslot * 16) ^ ((srow & 7) << 4);  // (srow+32)&7 == srow&7
    const size_t kOff0 = (size_t)srow * HD + (sB >> 1);
    const size_t kOff1 = kOff0 + (size_t)32 * HD;
    const size_t vOff0 = (size_t)srow * T_SEQ + (sB >> 1);
    const size_t vOff1 = vOff0 + (size_t)32 * T_SEQ;

    bf16x8 qf[2];
#pragma unroll
    for (int kd = 0; kd < 2; ++kd)
        qf[kd] = *(const bf16x8*)&Qh[(size_t)(qr0 + lr) * HD + kd * 32 + lg * 8];

    f32x4 oacc[4];
#pragma unroll
    for (int n = 0; n < 4; ++n) oacc[n] = (f32x4){0.f, 0.f, 0.f, 0.f};
    float m = -1e30f, lsum = 0.f;

    const int ntiles = bx + 1;

    // prologue: stage tile 0 -> buf 0
    async_copy16(Kh + kOff0, &Ks[0][tid * 8]);
    async_copy16(Kh + kOff1, &Ks[0][(tid + 256) * 8]);
    async_copy16(Vh + vOff0, &Vs[0][tid * 8]);
    async_copy16(Vh + vOff1, &Vs[0][(tid + 256) * 8]);
    __syncthreads();

    int cur = 0;
    for (int t = 0; t < ntiles; ++t) {
        const int kv0 = t * 64;
        if (t + 1 < ntiles) {  // issue next tile's loads; drained by loop-end barrier
            const size_t kb = (size_t)(t + 1) * 64 * HD;
            const size_t vb = (size_t)(t + 1) * 64;
            async_copy16(Kh + kb + kOff0, &Ks[cur ^ 1][tid * 8]);
            async_copy16(Kh + kb + kOff1, &Ks[cur ^ 1][(tid + 256) * 8]);
            async_copy16(Vh + vb + vOff0, &Vs[cur ^ 1][tid * 8]);
            async_copy16(Vh + vb + vOff1, &Vs[cur ^ 1][(tid + 256) * 8]);
        }
        {
            const __bf16* Ksc = &Ks[cur][0];
            const __bf16* Vsc = &Vs[cur][0];

            bf16x8 kf[4][2];
#pragma unroll
            for (int blk = 0; blk < 4; ++blk)
#pragma unroll
                for (int kd = 0; kd < 2; ++kd)
                    kf[blk][kd] = lds_read8(Ksc, blk * 16 + lr, kd * 64 + lg * 16);

            __builtin_amdgcn_s_setprio(1);
            f32x4 s[4];
#pragma unroll
            for (int blk = 0; blk < 4; ++blk) {
                f32x4 a = (f32x4){0.f, 0.f, 0.f, 0.f};
                a = mfma16(kf[blk][0], qf[0], a);
                a = mfma16(kf[blk][1], qf[1], a);
                s[blk] = a;
            }
            __builtin_amdgcn_s_setprio(0);

            float mx = -1e30f;
            if (kv0 + 63 > qr0) {  // diagonal tile: causal mask
#pragma unroll
                for (int blk = 0; blk < 4; ++blk)
#pragma unroll
                    for (int r = 0; r < 4; ++r) {
                        int kv = kv0 + 16 * blk + 4 * lg + r;
                        float sv = (kv <= qr0 + lr) ? s[blk][r] : -1e30f;
                        s[blk][r] = sv;
                        mx = fmaxf(mx, sv);
                    }
            } else {
#pragma unroll
                for (int blk = 0; blk < 4; ++blk)
#pragma unroll
                    for (int r = 0; r < 4; ++r) mx = fmaxf(mx, s[blk][r]);
            }
            mx = fmaxf(mx, __shfl_xor(mx, 16, 64));
            mx = fmaxf(mx, __shfl_xor(mx, 32, 64));

            // defer-max: skip rescale unless max grew by >8 (log2 units)
            if (!__all(mx <= m + 8.f)) {
                float mnew = fmaxf(m, mx);
                float alpha = exp2f(m - mnew);
                m = mnew;
                lsum *= alpha;
                float ar[4];
#pragma unroll
                for (int r = 0; r < 4; ++r) ar[r] = __shfl(alpha, 4 * lg + r, 64);
#pragma unroll
                for (int n = 0; n < 4; ++n)
#pragma unroll
                    for (int r = 0; r < 4; ++r) oacc[n][r] *= ar[r];
            }

            float ps = 0.f;
            char* pw = (char*)PsW + lr * 128;
            const int swz = (lr & 7) << 4;
#pragma unroll
            for (int blk = 0; blk < 4; ++blk) {
                bf16x4 pk;
#pragma unroll
                for (int r = 0; r < 4; ++r) {
                    float p = exp2f(s[blk][r] - m);
                    ps += p;
                    pk[r] = (__bf16)p;
                }
                *(bf16x4*)(pw + ((32 * blk + 8 * lg) ^ swz)) = pk;
            }
            ps += __shfl_xor(ps, 16, 64);
            ps += __shfl_xor(ps, 32, 64);
            lsum += ps;

            __builtin_amdgcn_s_setprio(1);
#pragma unroll
            for (int kc = 0; kc < 2; ++kc) {
                bf16x8 pa = lds_read8(PsW, lr, kc * 64 + lg * 16);
#pragma unroll
                for (int n = 0; n < 4; ++n) {
                    bf16x8 vb = lds_read8(Vsc, 16 * n + lr, kc * 64 + lg * 16);
                    oacc[n] = mfma16(pa, vb, oacc[n]);
                }
            }
            __builtin_amdgcn_s_setprio(0);
        }
        __syncthreads();  // drains next-tile loads + frees P/K/V bufs
        cur ^= 1;
    }

    float linv = 1.0f / lsum;
    float lrv[4];
#pragma unroll
    for (int r = 0; r < 4; ++r) lrv[r] = __shfl(linv, 4 * lg + r, 64);
#pragma unroll
    for (int n = 0; n < 4; ++n)
#pragma unroll
        for (int r = 0; r < 4; ++r) {
            int q = qr0 + 4 * lg + r;
            Og[(size_t)q * EMB + h * HD + 16 * n + lr] = (__bf16)(oacc[n][r] * lrv[r]);
        }
}

// ---------------------------------------------------------------------------
// GEMM2: out = AO @ woutT^T + b_out (fp32 out)
// ---------------------------------------------------------------------------
__global__ __launch_bounds__(256) void gemm_out_kernel(const __bf16* __restrict__ A,
                                                       const __bf16* __restrict__ Bt,
                                                       const float* __restrict__ bias,
                                                       float* __restrict__ out) {
    const int K = EMB;
    int m0 = blockIdx.y * 128, n0 = blockIdx.x * 128;
    int tid = threadIdx.x;
    int w = tid >> 6, l = tid & 63, lg = l >> 4, lr = l & 15;
    int wr = w >> 1, wc = w & 1;

    __shared__ __align__(16) __bf16 As[128 * 32];
    __shared__ __align__(16) __bf16 Bs[128 * 32];

    f32x4 acc[4][4];
#pragma unroll
    for (int mi = 0; mi < 4; ++mi)
#pragma unroll
        for (int ni = 0; ni < 4; ++ni) acc[mi][ni] = (f32x4){0.f, 0.f, 0.f, 0.f};

    for (int k0 = 0; k0 < K; k0 += 32) {
        __syncthreads();
#pragma unroll
        for (int i = 0; i < 2; ++i) {
            int flat = tid + 256 * i;
            int row = flat >> 2, c = flat & 3;
            async_copy16(&A[(size_t)(m0 + row) * K + k0 + c * 8], As + flat * 8);
            async_copy16(&Bt[(size_t)(n0 + row) * K + k0 + c * 8], Bs + flat * 8);
        }
        __syncthreads();
        bf16x8 af[4], bfr[4];
#pragma unroll
        for (int mi = 0; mi < 4; ++mi) af[mi] = *(const bf16x8*)(As + (wr * 64 + mi * 16 + lr) * 32 + lg * 8);
#pragma unroll
        for (int ni = 0; ni < 4; ++ni) bfr[ni] = *(const bf16x8*)(Bs + (wc * 64 + ni * 16 + lr) * 32 + lg * 8);
#pragma unroll
        for (int mi = 0; mi < 4; ++mi)
#pragma unroll
            for (int ni = 0; ni < 4; ++ni)
                acc[mi][ni] = mfma16(af[mi], bfr[ni], acc[mi][ni]);
    }

#pragma unroll
    for (int mi = 0; mi < 4; ++mi) {
#pragma unroll
        for (int ni = 0; ni < 4; ++ni) {
            int n = n0 + wc * 64 + ni * 16 + lr;
            float bv = bias[n];
#pragma unroll
            for (int r = 0; r < 4; ++r) {
                int mr = m0 + wr * 64 + mi * 16 + lg * 4 + r;
                out[(size_t)mr * EMB + n] = acc[mi][ni][r] + bv;
            }
        }
    }
}

// ---------------------------------------------------------------------------
extern "C" void kernel_launch(void* const* d_in, const int* in_sizes, int n_in,
                              void* d_out, int out_size, void* d_ws, size_t ws_size,
                              hipStream_t stream) {
    const float* x      = (const float*)d_in[0];
    const float* w_qkv  = (const float*)d_in[1];
    const float* b_qkv  = (const float*)d_in[2];
    const float* w_out  = (const float*)d_in[3];
    const float* b_out  = (const float*)d_in[4];
    float* out = (float*)d_out;

    char* ws = (char*)d_ws;
    __bf16* xb    = (__bf16*)(ws);                      // 8 MiB, reused as AO
    __bf16* AO    = (__bf16*)(ws);
    __bf16* wqkvT = (__bf16*)(ws + ((size_t)8 << 20));  // 6 MiB
    __bf16* woutT = (__bf16*)(ws + ((size_t)14 << 20)); // 2 MiB
    __bf16* Qh    = (__bf16*)(ws + ((size_t)16 << 20)); // 8 MiB
    __bf16* Kh    = (__bf16*)(ws + ((size_t)24 << 20)); // 8 MiB
    __bf16* Vh    = (__bf16*)(ws + ((size_t)32 << 20)); // 8 MiB
    __bf16* VTh   = (__bf16*)(ws + ((size_t)40 << 20)); // 8 MiB

    prep_kernel<<<dim3(8192), 256, 0, stream>>>(x, w_qkv, w_out, xb, wqkvT, woutT);

    gemm_qkv_kernel<<<dim3(N_QKV / 128, T_SEQ / 128), 256, 0, stream>>>(xb, wqkvT, b_qkv, Qh, Kh, Vh);

    vt_kernel<<<dim3(T_SEQ / 64, NH), 256, 0, stream>>>(Vh, VTh);

    attn_kernel<<<dim3(1024), 256, 0, stream>>>(Qh, Kh, VTh, AO);

    gemm_out_kernel<<<dim3(EMB / 128, T_SEQ / 128), 256, 0, stream>>>(AO, woutT, b_out, out);
}

// Round 5
// 227.004 us; speedup vs baseline: 1.7229x; 1.0214x over previous
//
#include <hip/hip_runtime.h>
#include <hip/hip_bf16.h>

// ---------------------------------------------------------------------------
// CausalSelfAttention: x[1,4096,1024] -> QKV -> 16-head causal attn -> out proj
// Round 4: shuffle-free softmax common path (lazy cross-lane max + deferred
//          lsum reduction) + paired q-tiles for perfectly uniform block work.
// ---------------------------------------------------------------------------

#define T_SEQ 4096
#define EMB   1024
#define NH    16
#define HD    64
#define N_QKV 3072

typedef __bf16 bf16x8 __attribute__((ext_vector_type(8)));
typedef __bf16 bf16x4 __attribute__((ext_vector_type(4)));
typedef float  f32x4  __attribute__((ext_vector_type(4)));

__device__ inline f32x4 mfma16(bf16x8 a, bf16x8 b, f32x4 c) {
    return __builtin_amdgcn_mfma_f32_16x16x32_bf16(a, b, c, 0, 0, 0);
}

__device__ inline void async_copy16(const void* g, void* l) {
    __builtin_amdgcn_global_load_lds(
        (const __attribute__((address_space(1))) unsigned int*)g,
        (__attribute__((address_space(3))) unsigned int*)l, 16, 0, 0);
}

// swizzled LDS read: 64-col bf16 rows (128B), byte ^= (row&7)<<4
__device__ inline bf16x8 lds_read8(const __bf16* base, int row, int colByte) {
    return *(const bf16x8*)((const char*)base + row * 128 +
                            (colByte ^ ((row & 7) << 4)));
}

// ---------------------------------------------------------------------------
// Fused prep: [0,4096) x->bf16 convert, [4096,7168) w_qkv transpose,
// [7168,8192) w_out transpose.
// ---------------------------------------------------------------------------
__global__ __launch_bounds__(256) void prep_kernel(const float* __restrict__ x,
                                                   const float* __restrict__ w_qkv,
                                                   const float* __restrict__ w_out,
                                                   __bf16* __restrict__ xb,
                                                   __bf16* __restrict__ wqkvT,
                                                   __bf16* __restrict__ woutT) {
    __shared__ __bf16 tl[32][33];
    int b = blockIdx.x;
    int t = threadIdx.x;
    if (b < 4096) {
        int i = (b * 256 + t) * 4;
        float4 v = *(const float4*)&x[i];
        bf16x4 o;
        o[0] = (__bf16)v.x; o[1] = (__bf16)v.y; o[2] = (__bf16)v.z; o[3] = (__bf16)v.w;
        *(bf16x4*)&xb[i] = o;
        return;
    }
    const float* in;
    __bf16* out;
    int N, bb;
    if (b < 7168) { bb = b - 4096; in = w_qkv; out = wqkvT; N = N_QKV; }
    else          { bb = b - 7168; in = w_out; out = woutT; N = EMB; }
    int k0 = (bb & 31) * 32, n0 = (bb >> 5) * 32;
    int r = t >> 3, c4 = (t & 7) * 4;
    float4 v = *(const float4*)&in[(size_t)(k0 + r) * N + n0 + c4];
    tl[r][c4 + 0] = (__bf16)v.x;
    tl[r][c4 + 1] = (__bf16)v.y;
    tl[r][c4 + 2] = (__bf16)v.z;
    tl[r][c4 + 3] = (__bf16)v.w;
    __syncthreads();
    bf16x4 o;
    o[0] = tl[c4 + 0][r];
    o[1] = tl[c4 + 1][r];
    o[2] = tl[c4 + 2][r];
    o[3] = tl[c4 + 3][r];
    *(bf16x4*)&out[(size_t)(n0 + r) * EMB + k0 + c4] = o;
}

// ---------------------------------------------------------------------------
// GEMM1: qkv = xb @ wqkvT^T + b_qkv. Q pre-scaled by 0.125*log2(e) (softmax
// runs in log2 domain). Q,K,V all written [h][t][d] coalesced.
// ---------------------------------------------------------------------------
__global__ __launch_bounds__(256) void gemm_qkv_kernel(const __bf16* __restrict__ A,
                                                       const __bf16* __restrict__ Bt,
                                                       const float* __restrict__ bias,
                                                       __bf16* __restrict__ Qo,
                                                       __bf16* __restrict__ Ko,
                                                       __bf16* __restrict__ Vo) {
    const int K = EMB;
    int m0 = blockIdx.y * 128, n0 = blockIdx.x * 128;
    int tid = threadIdx.x;
    int w = tid >> 6, l = tid & 63, lg = l >> 4, lr = l & 15;
    int wr = w >> 1, wc = w & 1;

    __shared__ __align__(16) __bf16 As[128 * 32];
    __shared__ __align__(16) __bf16 Bs[128 * 32];

    f32x4 acc[4][4];
#pragma unroll
    for (int mi = 0; mi < 4; ++mi)
#pragma unroll
        for (int ni = 0; ni < 4; ++ni) acc[mi][ni] = (f32x4){0.f, 0.f, 0.f, 0.f};

    for (int k0 = 0; k0 < K; k0 += 32) {
        __syncthreads();
#pragma unroll
        for (int i = 0; i < 2; ++i) {
            int flat = tid + 256 * i;
            int row = flat >> 2, c = flat & 3;
            async_copy16(&A[(size_t)(m0 + row) * K + k0 + c * 8], As + flat * 8);
            async_copy16(&Bt[(size_t)(n0 + row) * K + k0 + c * 8], Bs + flat * 8);
        }
        __syncthreads();
        bf16x8 af[4], bfr[4];
#pragma unroll
        for (int mi = 0; mi < 4; ++mi) af[mi] = *(const bf16x8*)(As + (wr * 64 + mi * 16 + lr) * 32 + lg * 8);
#pragma unroll
        for (int ni = 0; ni < 4; ++ni) bfr[ni] = *(const bf16x8*)(Bs + (wc * 64 + ni * 16 + lr) * 32 + lg * 8);
#pragma unroll
        for (int mi = 0; mi < 4; ++mi)
#pragma unroll
            for (int ni = 0; ni < 4; ++ni)
                acc[mi][ni] = mfma16(af[mi], bfr[ni], acc[mi][ni]);
    }

    const float QSC = 0.18033688011112042f;  // 0.125 * log2(e)
#pragma unroll
    for (int mi = 0; mi < 4; ++mi) {
#pragma unroll
        for (int ni = 0; ni < 4; ++ni) {
            int n = n0 + wc * 64 + ni * 16 + lr;
            float bv = bias[n];
            int mat = n >> 10, rem = n & 1023, hh = rem >> 6, d = rem & 63;
#pragma unroll
            for (int r = 0; r < 4; ++r) {
                int mr = m0 + wr * 64 + mi * 16 + lg * 4 + r;
                float v = acc[mi][ni][r] + bv;
                size_t idx = ((size_t)hh * T_SEQ + mr) * HD + d;
                if (mat == 0)      Qo[idx] = (__bf16)(v * QSC);
                else if (mat == 1) Ko[idx] = (__bf16)v;
                else               Vo[idx] = (__bf16)v;
            }
        }
    }
}

// ---------------------------------------------------------------------------
// V [h][t][d] -> VT [h][d][t]  (vectorized LDS transpose, 64x64 tiles)
// ---------------------------------------------------------------------------
__global__ __launch_bounds__(256) void vt_kernel(const __bf16* __restrict__ V,
                                                 __bf16* __restrict__ VT) {
    __shared__ __bf16 tl[64][72];
    int h = blockIdx.y, t0 = blockIdx.x * 64;
    int tid = threadIdx.x;
    const __bf16* Vh = V + (size_t)h * T_SEQ * HD;
#pragma unroll
    for (int i = 0; i < 2; ++i) {
        int flat = tid + 256 * i;
        int r = flat >> 3, sl = flat & 7;
        *(bf16x8*)&tl[r][sl * 8] = *(const bf16x8*)&Vh[(size_t)(t0 + r) * HD + sl * 8];
    }
    __syncthreads();
    __bf16* VTh = VT + (size_t)h * HD * T_SEQ;
#pragma unroll
    for (int i = 0; i < 2; ++i) {
        int flat = tid + 256 * i;
        int d = flat >> 3, sl = flat & 7;
        bf16x8 o;
#pragma unroll
        for (int j = 0; j < 8; ++j) o[j] = tl[sl * 8 + j][d];
        *(bf16x8*)&VTh[(size_t)d * T_SEQ + t0 + sl * 8] = o;
    }
}

// ---------------------------------------------------------------------------
// Flash attention, causal, log2 domain. 256 threads = 4 waves x 16 q-rows,
// QBLK=64. Each block processes TWO q-tiles (bx, 63-bx) -> exactly 66
// tile-units per block (perfect uniformity); 512 blocks, 2 heads per XCD.
// Double-buffered K/V via global_load_lds (swizzled); ONE barrier/tile.
// Shuffle-free softmax: in-lane max + __all lazy rescale; per-lane partial
// row-sums reduced once at phase end.
// ---------------------------------------------------------------------------
__global__ __launch_bounds__(256) void attn_kernel(const __bf16* __restrict__ Qg,
                                                   const __bf16* __restrict__ Kg,
                                                   const __bf16* __restrict__ VTg,
                                                   __bf16* __restrict__ Og) {
    __shared__ __align__(16) __bf16 Ks[2][64 * 64];
    __shared__ __align__(16) __bf16 Vs[2][64 * 64];
    __shared__ __align__(16) __bf16 Ps[4][16 * 64];

    const int bid = blockIdx.x;
    const int xcd = bid & 7, li = bid >> 3;
    const int h = xcd * 2 + (li & 1);   // 2 heads per XCD
    const int pr = li >> 1;             // 0..31 -> pair (63-pr, pr)
    const int tid = threadIdx.x;
    const int w = tid >> 6, l = tid & 63, lg = l >> 4, lr = l & 15;

    const __bf16* Qh = Qg + (size_t)h * T_SEQ * HD;
    const __bf16* Kh = Kg + (size_t)h * T_SEQ * HD;
    const __bf16* Vh = VTg + (size_t)h * HD * T_SEQ;
    __bf16* PsW = &Ps[w][0];

    // staging: 256 lanes x 16B = 32 rows per issue; 2 issues per 64-row tile
    const int srow = tid >> 3, sslot = tid & 7;
    const int sB = (sslot * 16) ^ ((srow & 7) << 4);  // (srow+32)&7 == srow&7
    const size_t kOff0 = (size_t)srow * HD + (sB >> 1);
    const size_t kOff1 = kOff0 + (size_t)32 * HD;
    const size_t vOff0 = (size_t)srow * T_SEQ + (sB >> 1);
    const size_t vOff1 = vOff0 + (size_t)32 * T_SEQ;

#pragma unroll 1
    for (int ph = 0; ph < 2; ++ph) {
        const int bx = ph ? pr : (63 - pr);
        const int qr0 = bx * 64 + 16 * w;

        bf16x8 qf[2];
#pragma unroll
        for (int kd = 0; kd < 2; ++kd)
            qf[kd] = *(const bf16x8*)&Qh[(size_t)(qr0 + lr) * HD + kd * 32 + lg * 8];

        f32x4 oacc[4];
#pragma unroll
        for (int n = 0; n < 4; ++n) oacc[n] = (f32x4){0.f, 0.f, 0.f, 0.f};
        float m = -1e30f, lsum = 0.f;

        const int ntiles = bx + 1;

        // prologue: stage tile 0 -> buf 0
        async_copy16(Kh + kOff0, &Ks[0][tid * 8]);
        async_copy16(Kh + kOff1, &Ks[0][(tid + 256) * 8]);
        async_copy16(Vh + vOff0, &Vs[0][tid * 8]);
        async_copy16(Vh + vOff1, &Vs[0][(tid + 256) * 8]);
        __syncthreads();

        int cur = 0;
        for (int t = 0; t < ntiles; ++t) {
            const int kv0 = t * 64;
            if (t + 1 < ntiles) {  // next tile's loads; drained by loop-end barrier
                const size_t kb = (size_t)(t + 1) * 64 * HD;
                const size_t vb = (size_t)(t + 1) * 64;
                async_copy16(Kh + kb + kOff0, &Ks[cur ^ 1][tid * 8]);
                async_copy16(Kh + kb + kOff1, &Ks[cur ^ 1][(tid + 256) * 8]);
                async_copy16(Vh + vb + vOff0, &Vs[cur ^ 1][tid * 8]);
                async_copy16(Vh + vb + vOff1, &Vs[cur ^ 1][(tid + 256) * 8]);
            }
            const __bf16* Ksc = &Ks[cur][0];
            const __bf16* Vsc = &Vs[cur][0];

            bf16x8 kf[4][2];
#pragma unroll
            for (int blk = 0; blk < 4; ++blk)
#pragma unroll
                for (int kd = 0; kd < 2; ++kd)
                    kf[blk][kd] = lds_read8(Ksc, blk * 16 + lr, kd * 64 + lg * 16);

            __builtin_amdgcn_s_setprio(1);
            f32x4 s[4];
#pragma unroll
            for (int blk = 0; blk < 4; ++blk) {
                f32x4 a = (f32x4){0.f, 0.f, 0.f, 0.f};
                a = mfma16(kf[blk][0], qf[0], a);
                a = mfma16(kf[blk][1], qf[1], a);
                s[blk] = a;
            }
            __builtin_amdgcn_s_setprio(0);

            // in-lane max (cross-lane only on rescale events)
            float mx = -1e30f;
            if (kv0 + 63 > qr0) {  // diagonal tile: causal mask
#pragma unroll
                for (int blk = 0; blk < 4; ++blk)
#pragma unroll
                    for (int r = 0; r < 4; ++r) {
                        int kv = kv0 + 16 * blk + 4 * lg + r;
                        float sv = (kv <= qr0 + lr) ? s[blk][r] : -1e30f;
                        s[blk][r] = sv;
                        mx = fmaxf(mx, sv);
                    }
            } else {
#pragma unroll
                for (int blk = 0; blk < 4; ++blk)
#pragma unroll
                    for (int r = 0; r < 4; ++r) mx = fmaxf(mx, s[blk][r]);
            }

            // lazy rescale: only when some lane's local max grew past m+8.
            // m stays row-uniform between events, so per-lane partial sums
            // stay consistently scaled. Tile 0 always triggers (m=-1e30).
            if (!__all(mx <= m + 8.f)) {
                float mf = fmaxf(mx, __shfl_xor(mx, 16, 64));
                mf = fmaxf(mf, __shfl_xor(mf, 32, 64));
                float mnew = fmaxf(m, mf);
                float alpha = exp2f(m - mnew);
                m = mnew;
                lsum *= alpha;
                float ar[4];
#pragma unroll
                for (int r = 0; r < 4; ++r) ar[r] = __shfl(alpha, 4 * lg + r, 64);
#pragma unroll
                for (int n = 0; n < 4; ++n)
#pragma unroll
                    for (int r = 0; r < 4; ++r) oacc[n][r] *= ar[r];
            }

            // exp + per-lane partial sum (no cross-lane)
            float ps = 0.f;
            char* pw = (char*)PsW + lr * 128;
            const int swz = (lr & 7) << 4;
#pragma unroll
            for (int blk = 0; blk < 4; ++blk) {
                bf16x4 pk;
#pragma unroll
                for (int r = 0; r < 4; ++r) {
                    float p = exp2f(s[blk][r] - m);
                    ps += p;
                    pk[r] = (__bf16)p;
                }
                *(bf16x4*)(pw + ((32 * blk + 8 * lg) ^ swz)) = pk;
            }
            lsum += ps;

            __builtin_amdgcn_s_setprio(1);
#pragma unroll
            for (int kc = 0; kc < 2; ++kc) {
                bf16x8 pa = lds_read8(PsW, lr, kc * 64 + lg * 16);
#pragma unroll
                for (int n = 0; n < 4; ++n) {
                    bf16x8 vb = lds_read8(Vsc, 16 * n + lr, kc * 64 + lg * 16);
                    oacc[n] = mfma16(pa, vb, oacc[n]);
                }
            }
            __builtin_amdgcn_s_setprio(0);

            __syncthreads();  // drains next-tile loads + frees P/K/V bufs
            cur ^= 1;
        }

        // final cross-lane reduction of row-sum partials (once per phase)
        lsum += __shfl_xor(lsum, 16, 64);
        lsum += __shfl_xor(lsum, 32, 64);
        float linv = 1.0f / lsum;
        float lrv[4];
#pragma unroll
        for (int r = 0; r < 4; ++r) lrv[r] = __shfl(linv, 4 * lg + r, 64);
#pragma unroll
        for (int n = 0; n < 4; ++n)
#pragma unroll
            for (int r = 0; r < 4; ++r) {
                int q = qr0 + 4 * lg + r;
                Og[(size_t)q * EMB + h * HD + 16 * n + lr] = (__bf16)(oacc[n][r] * lrv[r]);
            }
    }
}

// ---------------------------------------------------------------------------
// GEMM2: out = AO @ woutT^T + b_out (fp32 out)
// ---------------------------------------------------------------------------
__global__ __launch_bounds__(256) void gemm_out_kernel(const __bf16* __restrict__ A,
                                                       const __bf16* __restrict__ Bt,
                                                       const float* __restrict__ bias,
                                                       float* __restrict__ out) {
    const int K = EMB;
    int m0 = blockIdx.y * 128, n0 = blockIdx.x * 128;
    int tid = threadIdx.x;
    int w = tid >> 6, l = tid & 63, lg = l >> 4, lr = l & 15;
    int wr = w >> 1, wc = w & 1;

    __shared__ __align__(16) __bf16 As[128 * 32];
    __shared__ __align__(16) __bf16 Bs[128 * 32];

    f32x4 acc[4][4];
#pragma unroll
    for (int mi = 0; mi < 4; ++mi)
#pragma unroll
        for (int ni = 0; ni < 4; ++ni) acc[mi][ni] = (f32x4){0.f, 0.f, 0.f, 0.f};

    for (int k0 = 0; k0 < K; k0 += 32) {
        __syncthreads();
#pragma unroll
        for (int i = 0; i < 2; ++i) {
            int flat = tid + 256 * i;
            int row = flat >> 2, c = flat & 3;
            async_copy16(&A[(size_t)(m0 + row) * K + k0 + c * 8], As + flat * 8);
            async_copy16(&Bt[(size_t)(n0 + row) * K + k0 + c * 8], Bs + flat * 8);
        }
        __syncthreads();
        bf16x8 af[4], bfr[4];
#pragma unroll
        for (int mi = 0; mi < 4; ++mi) af[mi] = *(const bf16x8*)(As + (wr * 64 + mi * 16 + lr) * 32 + lg * 8);
#pragma unroll
        for (int ni = 0; ni < 4; ++ni) bfr[ni] = *(const bf16x8*)(Bs + (wc * 64 + ni * 16 + lr) * 32 + lg * 8);
#pragma unroll
        for (int mi = 0; mi < 4; ++mi)
#pragma unroll
            for (int ni = 0; ni < 4; ++ni)
                acc[mi][ni] = mfma16(af[mi], bfr[ni], acc[mi][ni]);
    }

#pragma unroll
    for (int mi = 0; mi < 4; ++mi) {
#pragma unroll
        for (int ni = 0; ni < 4; ++ni) {
            int n = n0 + wc * 64 + ni * 16 + lr;
            float bv = bias[n];
#pragma unroll
            for (int r = 0; r < 4; ++r) {
                int mr = m0 + wr * 64 + mi * 16 + lg * 4 + r;
                out[(size_t)mr * EMB + n] = acc[mi][ni][r] + bv;
            }
        }
    }
}

// ---------------------------------------------------------------------------
extern "C" void kernel_launch(void* const* d_in, const int* in_sizes, int n_in,
                              void* d_out, int out_size, void* d_ws, size_t ws_size,
                              hipStream_t stream) {
    const float* x      = (const float*)d_in[0];
    const float* w_qkv  = (const float*)d_in[1];
    const float* b_qkv  = (const float*)d_in[2];
    const float* w_out  = (const float*)d_in[3];
    const float* b_out  = (const float*)d_in[4];
    float* out = (float*)d_out;

    char* ws = (char*)d_ws;
    __bf16* xb    = (__bf16*)(ws);                      // 8 MiB, reused as AO
    __bf16* AO    = (__bf16*)(ws);
    __bf16* wqkvT = (__bf16*)(ws + ((size_t)8 << 20));  // 6 MiB
    __bf16* woutT = (__bf16*)(ws + ((size_t)14 << 20)); // 2 MiB
    __bf16* Qh    = (__bf16*)(ws + ((size_t)16 << 20)); // 8 MiB
    __bf16* Kh    = (__bf16*)(ws + ((size_t)24 << 20)); // 8 MiB
    __bf16* Vh    = (__bf16*)(ws + ((size_t)32 << 20)); // 8 MiB
    __bf16* VTh   = (__bf16*)(ws + ((size_t)40 << 20)); // 8 MiB

    prep_kernel<<<dim3(8192), 256, 0, stream>>>(x, w_qkv, w_out, xb, wqkvT, woutT);

    gemm_qkv_kernel<<<dim3(N_QKV / 128, T_SEQ / 128), 256, 0, stream>>>(xb, wqkvT, b_qkv, Qh, Kh, Vh);

    vt_kernel<<<dim3(T_SEQ / 64, NH), 256, 0, stream>>>(Vh, VTh);

    attn_kernel<<<dim3(512), 256, 0, stream>>>(Qh, Kh, VTh, AO);

    gemm_out_kernel<<<dim3(EMB / 128, T_SEQ / 128), 256, 0, stream>>>(AO, woutT, b_out, out);
}

// Round 6
// 224.921 us; speedup vs baseline: 1.7389x; 1.0093x over previous
//
#include <hip/hip_runtime.h>
#include <hip/hip_bf16.h>

// ---------------------------------------------------------------------------
// CausalSelfAttention: x[1,4096,1024] -> QKV -> 16-head causal attn -> out proj
// Round 6: attn rebuilt — 8 waves x 128 q-rows, 2 blocks/CU, KV loop unrolled
//          x2 with static buffers so ALL LDS addressing is loop-invariant
//          (base VGPR + immediate). Softmax math unchanged (lazy rescale).
// ---------------------------------------------------------------------------

#define T_SEQ 4096
#define EMB   1024
#define NH    16
#define HD    64
#define N_QKV 3072

typedef __bf16 bf16x8 __attribute__((ext_vector_type(8)));
typedef __bf16 bf16x4 __attribute__((ext_vector_type(4)));
typedef float  f32x4  __attribute__((ext_vector_type(4)));

__device__ inline f32x4 mfma16(bf16x8 a, bf16x8 b, f32x4 c) {
    return __builtin_amdgcn_mfma_f32_16x16x32_bf16(a, b, c, 0, 0, 0);
}

__device__ inline void async_copy16(const void* g, void* l) {
    __builtin_amdgcn_global_load_lds(
        (const __attribute__((address_space(1))) unsigned int*)g,
        (__attribute__((address_space(3))) unsigned int*)l, 16, 0, 0);
}

// swizzled LDS read (used by GEMMs only now)
__device__ inline bf16x8 lds_read8(const __bf16* base, int row, int colByte) {
    return *(const bf16x8*)((const char*)base + row * 128 +
                            (colByte ^ ((row & 7) << 4)));
}

// ---------------------------------------------------------------------------
// Fused prep: [0,4096) x->bf16 convert, [4096,7168) w_qkv transpose,
// [7168,8192) w_out transpose.
// ---------------------------------------------------------------------------
__global__ __launch_bounds__(256) void prep_kernel(const float* __restrict__ x,
                                                   const float* __restrict__ w_qkv,
                                                   const float* __restrict__ w_out,
                                                   __bf16* __restrict__ xb,
                                                   __bf16* __restrict__ wqkvT,
                                                   __bf16* __restrict__ woutT) {
    __shared__ __bf16 tl[32][33];
    int b = blockIdx.x;
    int t = threadIdx.x;
    if (b < 4096) {
        int i = (b * 256 + t) * 4;
        float4 v = *(const float4*)&x[i];
        bf16x4 o;
        o[0] = (__bf16)v.x; o[1] = (__bf16)v.y; o[2] = (__bf16)v.z; o[3] = (__bf16)v.w;
        *(bf16x4*)&xb[i] = o;
        return;
    }
    const float* in;
    __bf16* out;
    int N, bb;
    if (b < 7168) { bb = b - 4096; in = w_qkv; out = wqkvT; N = N_QKV; }
    else          { bb = b - 7168; in = w_out; out = woutT; N = EMB; }
    int k0 = (bb & 31) * 32, n0 = (bb >> 5) * 32;
    int r = t >> 3, c4 = (t & 7) * 4;
    float4 v = *(const float4*)&in[(size_t)(k0 + r) * N + n0 + c4];
    tl[r][c4 + 0] = (__bf16)v.x;
    tl[r][c4 + 1] = (__bf16)v.y;
    tl[r][c4 + 2] = (__bf16)v.z;
    tl[r][c4 + 3] = (__bf16)v.w;
    __syncthreads();
    bf16x4 o;
    o[0] = tl[c4 + 0][r];
    o[1] = tl[c4 + 1][r];
    o[2] = tl[c4 + 2][r];
    o[3] = tl[c4 + 3][r];
    *(bf16x4*)&out[(size_t)(n0 + r) * EMB + k0 + c4] = o;
}

// ---------------------------------------------------------------------------
// GEMM1: qkv = xb @ wqkvT^T + b_qkv. Q pre-scaled by 0.125*log2(e).
// ---------------------------------------------------------------------------
__global__ __launch_bounds__(256) void gemm_qkv_kernel(const __bf16* __restrict__ A,
                                                       const __bf16* __restrict__ Bt,
                                                       const float* __restrict__ bias,
                                                       __bf16* __restrict__ Qo,
                                                       __bf16* __restrict__ Ko,
                                                       __bf16* __restrict__ Vo) {
    const int K = EMB;
    int m0 = blockIdx.y * 128, n0 = blockIdx.x * 128;
    int tid = threadIdx.x;
    int w = tid >> 6, l = tid & 63, lg = l >> 4, lr = l & 15;
    int wr = w >> 1, wc = w & 1;

    __shared__ __align__(16) __bf16 As[128 * 32];
    __shared__ __align__(16) __bf16 Bs[128 * 32];

    f32x4 acc[4][4];
#pragma unroll
    for (int mi = 0; mi < 4; ++mi)
#pragma unroll
        for (int ni = 0; ni < 4; ++ni) acc[mi][ni] = (f32x4){0.f, 0.f, 0.f, 0.f};

    for (int k0 = 0; k0 < K; k0 += 32) {
        __syncthreads();
#pragma unroll
        for (int i = 0; i < 2; ++i) {
            int flat = tid + 256 * i;
            int row = flat >> 2, c = flat & 3;
            async_copy16(&A[(size_t)(m0 + row) * K + k0 + c * 8], As + flat * 8);
            async_copy16(&Bt[(size_t)(n0 + row) * K + k0 + c * 8], Bs + flat * 8);
        }
        __syncthreads();
        bf16x8 af[4], bfr[4];
#pragma unroll
        for (int mi = 0; mi < 4; ++mi) af[mi] = *(const bf16x8*)(As + (wr * 64 + mi * 16 + lr) * 32 + lg * 8);
#pragma unroll
        for (int ni = 0; ni < 4; ++ni) bfr[ni] = *(const bf16x8*)(Bs + (wc * 64 + ni * 16 + lr) * 32 + lg * 8);
#pragma unroll
        for (int mi = 0; mi < 4; ++mi)
#pragma unroll
            for (int ni = 0; ni < 4; ++ni)
                acc[mi][ni] = mfma16(af[mi], bfr[ni], acc[mi][ni]);
    }

    const float QSC = 0.18033688011112042f;  // 0.125 * log2(e)
#pragma unroll
    for (int mi = 0; mi < 4; ++mi) {
#pragma unroll
        for (int ni = 0; ni < 4; ++ni) {
            int n = n0 + wc * 64 + ni * 16 + lr;
            float bv = bias[n];
            int mat = n >> 10, rem = n & 1023, hh = rem >> 6, d = rem & 63;
#pragma unroll
            for (int r = 0; r < 4; ++r) {
                int mr = m0 + wr * 64 + mi * 16 + lg * 4 + r;
                float v = acc[mi][ni][r] + bv;
                size_t idx = ((size_t)hh * T_SEQ + mr) * HD + d;
                if (mat == 0)      Qo[idx] = (__bf16)(v * QSC);
                else if (mat == 1) Ko[idx] = (__bf16)v;
                else               Vo[idx] = (__bf16)v;
            }
        }
    }
}

// ---------------------------------------------------------------------------
// V [h][t][d] -> VT [h][d][t]
// ---------------------------------------------------------------------------
__global__ __launch_bounds__(256) void vt_kernel(const __bf16* __restrict__ V,
                                                 __bf16* __restrict__ VT) {
    __shared__ __bf16 tl[64][72];
    int h = blockIdx.y, t0 = blockIdx.x * 64;
    int tid = threadIdx.x;
    const __bf16* Vh = V + (size_t)h * T_SEQ * HD;
#pragma unroll
    for (int i = 0; i < 2; ++i) {
        int flat = tid + 256 * i;
        int r = flat >> 3, sl = flat & 7;
        *(bf16x8*)&tl[r][sl * 8] = *(const bf16x8*)&Vh[(size_t)(t0 + r) * HD + sl * 8];
    }
    __syncthreads();
    __bf16* VTh = VT + (size_t)h * HD * T_SEQ;
#pragma unroll
    for (int i = 0; i < 2; ++i) {
        int flat = tid + 256 * i;
        int d = flat >> 3, sl = flat & 7;
        bf16x8 o;
#pragma unroll
        for (int j = 0; j < 8; ++j) o[j] = tl[sl * 8 + j][d];
        *(bf16x8*)&VTh[(size_t)d * T_SEQ + t0 + sl * 8] = o;
    }
}

// ---------------------------------------------------------------------------
// Flash attention, causal, log2 domain. 512 threads = 8 waves x 16 q-rows
// (QBLK=128). 512 blocks = 2/CU; mapping pairs (i, i+16) on one CU -> uniform
// 34 tile-units/CU, same head for L2 reuse, heavy-first. KV loop unrolled x2
// with STATIC buffers: all LDS addresses are hoisted lane constants + imm.
// ---------------------------------------------------------------------------
__global__ __launch_bounds__(512, 4) void attn_kernel(const __bf16* __restrict__ Qg,
                                                      const __bf16* __restrict__ Kg,
                                                      const __bf16* __restrict__ VTg,
                                                      __bf16* __restrict__ Og) {
    __shared__ __align__(16) __bf16 Ks[2][64 * 64];   // +8192B between bufs
    __shared__ __align__(16) __bf16 Vs[2][64 * 64];
    __shared__ __align__(16) __bf16 Ps[8][16 * 64];   // 2048B per wave

    const int bid = blockIdx.x;
    const int h = bid & 15;                 // bid+256 keeps same head on same CU
    const int i = bid >> 4;                 // 0..31
    const int bx = (i < 16) ? (31 - i) : (i - 16);  // heavy first; CU pair sums 32
    const int tid = threadIdx.x;
    const int w = tid >> 6, l = tid & 63, lg = l >> 4, lr = l & 15;
    const int qr0 = bx * 128 + 16 * w;

    const __bf16* Qh = Qg + (size_t)h * T_SEQ * HD;
    const __bf16* Kh = Kg + (size_t)h * T_SEQ * HD;
    const __bf16* Vh = VTg + (size_t)h * HD * T_SEQ;

    // staging: 512 lanes x 16B = one full 64x64 bf16 tile per issue
    const int srow = tid >> 3, sslot = tid & 7;
    const int sB = (sslot * 16) ^ ((srow & 7) << 4);
    const __bf16* kSrc = Kh + (size_t)srow * HD + (sB >> 1);    // += 64*HD/tile
    const __bf16* vSrc = Vh + (size_t)srow * T_SEQ + (sB >> 1); // += 64/tile

    // loop-invariant LDS bases (byte pointers); buf -> +8192, blk/n -> +2048
    const int coff0 = (lg * 16) ^ ((lr & 7) << 4);
    const int coff1 = coff0 ^ 64;
    const char* KB0 = (const char*)Ks + lr * 128 + coff0;
    const char* KB1 = (const char*)Ks + lr * 128 + coff1;
    const char* VB0 = (const char*)Vs + lr * 128 + coff0;
    const char* VB1 = (const char*)Vs + lr * 128 + coff1;
    char* PW = (char*)Ps + w * 2048 + lr * 128;
    const char* PA0 = PW + coff0;
    const char* PA1 = PW + coff1;
    char* pwr0 = PW + ((0  + 8 * lg) ^ ((lr & 7) << 4));
    char* pwr1 = PW + ((32 + 8 * lg) ^ ((lr & 7) << 4));
    char* pwr2 = PW + ((64 + 8 * lg) ^ ((lr & 7) << 4));
    char* pwr3 = PW + ((96 + 8 * lg) ^ ((lr & 7) << 4));

    bf16x8 qf[2];
#pragma unroll
    for (int kd = 0; kd < 2; ++kd)
        qf[kd] = *(const bf16x8*)&Qh[(size_t)(qr0 + lr) * HD + kd * 32 + lg * 8];

    f32x4 oacc[4];
#pragma unroll
    for (int n = 0; n < 4; ++n) oacc[n] = (f32x4){0.f, 0.f, 0.f, 0.f};
    float m = -1e30f, lsum = 0.f;

    const int ntiles = 2 * bx + 2;  // always even

#define ATTN_STAGE(BUF)                                          \
    do {                                                         \
        async_copy16(kSrc, &Ks[BUF][tid * 8]);                   \
        async_copy16(vSrc, &Vs[BUF][tid * 8]);                   \
        kSrc += 64 * HD;                                         \
        vSrc += 64;                                              \
    } while (0)

#define ATTN_TILE(BUF, KV0)                                                       \
    if ((KV0) <= qr0 + 15) {                                                      \
        bf16x8 kf[4][2];                                                          \
        _Pragma("unroll") for (int blk = 0; blk < 4; ++blk) {                     \
            kf[blk][0] = *(const bf16x8*)(KB0 + (BUF) * 8192 + blk * 2048);       \
            kf[blk][1] = *(const bf16x8*)(KB1 + (BUF) * 8192 + blk * 2048);       \
        }                                                                         \
        __builtin_amdgcn_s_setprio(1);                                            \
        f32x4 s[4];                                                               \
        _Pragma("unroll") for (int blk = 0; blk < 4; ++blk) {                     \
            f32x4 a = (f32x4){0.f, 0.f, 0.f, 0.f};                                \
            a = mfma16(kf[blk][0], qf[0], a);                                     \
            a = mfma16(kf[blk][1], qf[1], a);                                     \
            s[blk] = a;                                                           \
        }                                                                         \
        __builtin_amdgcn_s_setprio(0);                                            \
        float mx = -1e30f;                                                        \
        if ((KV0) + 63 > qr0) {                                                   \
            _Pragma("unroll") for (int blk = 0; blk < 4; ++blk)                   \
                _Pragma("unroll") for (int r = 0; r < 4; ++r) {                   \
                    int kv = (KV0) + 16 * blk + 4 * lg + r;                       \
                    float sv = (kv <= qr0 + lr) ? s[blk][r] : -1e30f;             \
                    s[blk][r] = sv;                                               \
                    mx = fmaxf(mx, sv);                                           \
                }                                                                 \
        } else {                                                                  \
            _Pragma("unroll") for (int blk = 0; blk < 4; ++blk)                   \
                _Pragma("unroll") for (int r = 0; r < 4; ++r)                     \
                    mx = fmaxf(mx, s[blk][r]);                                    \
        }                                                                         \
        if (!__all(mx <= m + 8.f)) {                                              \
            float mf = fmaxf(mx, __shfl_xor(mx, 16, 64));                         \
            mf = fmaxf(mf, __shfl_xor(mf, 32, 64));                               \
            float mnew = fmaxf(m, mf);                                            \
            float alpha = exp2f(m - mnew);                                        \
            m = mnew;                                                             \
            lsum *= alpha;                                                        \
            float ar[4];                                                          \
            _Pragma("unroll") for (int r = 0; r < 4; ++r)                         \
                ar[r] = __shfl(alpha, 4 * lg + r, 64);                            \
            _Pragma("unroll") for (int n = 0; n < 4; ++n)                         \
                _Pragma("unroll") for (int r = 0; r < 4; ++r)                     \
                    oacc[n][r] *= ar[r];                                          \
        }                                                                         \
        {                                                                         \
            float ps = 0.f;                                                       \
            bf16x4 pk0, pk1, pk2, pk3;                                            \
            _Pragma("unroll") for (int r = 0; r < 4; ++r) {                       \
                float p0 = exp2f(s[0][r] - m); ps += p0; pk0[r] = (__bf16)p0;     \
                float p1 = exp2f(s[1][r] - m); ps += p1; pk1[r] = (__bf16)p1;     \
                float p2 = exp2f(s[2][r] - m); ps += p2; pk2[r] = (__bf16)p2;     \
                float p3 = exp2f(s[3][r] - m); ps += p3; pk3[r] = (__bf16)p3;     \
            }                                                                     \
            *(bf16x4*)pwr0 = pk0;                                                 \
            *(bf16x4*)pwr1 = pk1;                                                 \
            *(bf16x4*)pwr2 = pk2;                                                 \
            *(bf16x4*)pwr3 = pk3;                                                 \
            lsum += ps;                                                           \
        }                                                                         \
        {                                                                         \
            bf16x8 pa0 = *(const bf16x8*)PA0;                                     \
            bf16x8 pa1 = *(const bf16x8*)PA1;                                     \
            __builtin_amdgcn_s_setprio(1);                                        \
            _Pragma("unroll") for (int n = 0; n < 4; ++n) {                       \
                bf16x8 vb0 = *(const bf16x8*)(VB0 + (BUF) * 8192 + n * 2048);     \
                bf16x8 vb1 = *(const bf16x8*)(VB1 + (BUF) * 8192 + n * 2048);     \
                oacc[n] = mfma16(pa0, vb0, oacc[n]);                              \
                oacc[n] = mfma16(pa1, vb1, oacc[n]);                              \
            }                                                                     \
            __builtin_amdgcn_s_setprio(0);                                        \
        }                                                                         \
    }

    // prologue: stage tile 0 -> buf 0
    ATTN_STAGE(0);
    __syncthreads();

    for (int t = 0; t < ntiles; t += 2) {
        ATTN_STAGE(1);            // tile t+1 (exists: ntiles even)
        ATTN_TILE(0, t * 64)
        __syncthreads();          // drains buf1 loads; frees buf0
        if (t + 2 < ntiles) ATTN_STAGE(0);  // tile t+2
        ATTN_TILE(1, (t + 1) * 64)
        __syncthreads();          // drains buf0 loads; frees buf1
    }

#undef ATTN_STAGE
#undef ATTN_TILE

    // final cross-lane reduction of row-sum partials
    lsum += __shfl_xor(lsum, 16, 64);
    lsum += __shfl_xor(lsum, 32, 64);
    float linv = 1.0f / lsum;
    float lrv[4];
#pragma unroll
    for (int r = 0; r < 4; ++r) lrv[r] = __shfl(linv, 4 * lg + r, 64);
#pragma unroll
    for (int n = 0; n < 4; ++n)
#pragma unroll
        for (int r = 0; r < 4; ++r) {
            int q = qr0 + 4 * lg + r;
            Og[(size_t)q * EMB + h * HD + 16 * n + lr] = (__bf16)(oacc[n][r] * lrv[r]);
        }
}

// ---------------------------------------------------------------------------
// GEMM2: out = AO @ woutT^T + b_out (fp32 out)
// ---------------------------------------------------------------------------
__global__ __launch_bounds__(256) void gemm_out_kernel(const __bf16* __restrict__ A,
                                                       const __bf16* __restrict__ Bt,
                                                       const float* __restrict__ bias,
                                                       float* __restrict__ out) {
    const int K = EMB;
    int m0 = blockIdx.y * 128, n0 = blockIdx.x * 128;
    int tid = threadIdx.x;
    int w = tid >> 6, l = tid & 63, lg = l >> 4, lr = l & 15;
    int wr = w >> 1, wc = w & 1;

    __shared__ __align__(16) __bf16 As[128 * 32];
    __shared__ __align__(16) __bf16 Bs[128 * 32];

    f32x4 acc[4][4];
#pragma unroll
    for (int mi = 0; mi < 4; ++mi)
#pragma unroll
        for (int ni = 0; ni < 4; ++ni) acc[mi][ni] = (f32x4){0.f, 0.f, 0.f, 0.f};

    for (int k0 = 0; k0 < K; k0 += 32) {
        __syncthreads();
#pragma unroll
        for (int i = 0; i < 2; ++i) {
            int flat = tid + 256 * i;
            int row = flat >> 2, c = flat & 3;
            async_copy16(&A[(size_t)(m0 + row) * K + k0 + c * 8], As + flat * 8);
            async_copy16(&Bt[(size_t)(n0 + row) * K + k0 + c * 8], Bs + flat * 8);
        }
        __syncthreads();
        bf16x8 af[4], bfr[4];
#pragma unroll
        for (int mi = 0; mi < 4; ++mi) af[mi] = *(const bf16x8*)(As + (wr * 64 + mi * 16 + lr) * 32 + lg * 8);
#pragma unroll
        for (int ni = 0; ni < 4; ++ni) bfr[ni] = *(const bf16x8*)(Bs + (wc * 64 + ni * 16 + lr) * 32 + lg * 8);
#pragma unroll
        for (int mi = 0; mi < 4; ++mi)
#pragma unroll
            for (int ni = 0; ni < 4; ++ni)
                acc[mi][ni] = mfma16(af[mi], bfr[ni], acc[mi][ni]);
    }

#pragma unroll
    for (int mi = 0; mi < 4; ++mi) {
#pragma unroll
        for (int ni = 0; ni < 4; ++ni) {
            int n = n0 + wc * 64 + ni * 16 + lr;
            float bv = bias[n];
#pragma unroll
            for (int r = 0; r < 4; ++r) {
                int mr = m0 + wr * 64 + mi * 16 + lg * 4 + r;
                out[(size_t)mr * EMB + n] = acc[mi][ni][r] + bv;
            }
        }
    }
}

// ---------------------------------------------------------------------------
extern "C" void kernel_launch(void* const* d_in, const int* in_sizes, int n_in,
                              void* d_out, int out_size, void* d_ws, size_t ws_size,
                              hipStream_t stream) {
    const float* x      = (const float*)d_in[0];
    const float* w_qkv  = (const float*)d_in[1];
    const float* b_qkv  = (const float*)d_in[2];
    const float* w_out  = (const float*)d_in[3];
    const float* b_out  = (const float*)d_in[4];
    float* out = (float*)d_out;

    char* ws = (char*)d_ws;
    __bf16* xb    = (__bf16*)(ws);                      // 8 MiB, reused as AO
    __bf16* AO    = (__bf16*)(ws);
    __bf16* wqkvT = (__bf16*)(ws + ((size_t)8 << 20));  // 6 MiB
    __bf16* woutT = (__bf16*)(ws + ((size_t)14 << 20)); // 2 MiB
    __bf16* Qh    = (__bf16*)(ws + ((size_t)16 << 20)); // 8 MiB
    __bf16* Kh    = (__bf16*)(ws + ((size_t)24 << 20)); // 8 MiB
    __bf16* Vh    = (__bf16*)(ws + ((size_t)32 << 20)); // 8 MiB
    __bf16* VTh   = (__bf16*)(ws + ((size_t)40 << 20)); // 8 MiB

    prep_kernel<<<dim3(8192), 256, 0, stream>>>(x, w_qkv, w_out, xb, wqkvT, woutT);

    gemm_qkv_kernel<<<dim3(N_QKV / 128, T_SEQ / 128), 256, 0, stream>>>(xb, wqkvT, b_qkv, Qh, Kh, Vh);

    vt_kernel<<<dim3(T_SEQ / 64, NH), 256, 0, stream>>>(Vh, VTh);

    attn_kernel<<<dim3(512), 512, 0, stream>>>(Qh, Kh, VTh, AO);

    gemm_out_kernel<<<dim3(EMB / 128, T_SEQ / 128), 256, 0, stream>>>(AO, woutT, b_out, out);
}